// Round 7
// baseline (280.735 us; speedup 1.0000x reference)
//
#include <hip/hip_runtime.h>
#include <hip/hip_bf16.h>

#define DIM 256
#define HEADS 8
#define DHEAD 32
#define SEQ 2048
#define BATCH 2
#define NROWS (BATCH*SEQ)    // 4096 total rows
#define EPS 1e-5f

typedef __attribute__((ext_vector_type(8))) short bf16x8;   // MFMA A/B frag (4 VGPRs)
typedef __attribute__((ext_vector_type(4))) short bf16x4;   // 4 bf16 (8B)
typedef __attribute__((ext_vector_type(4))) float f32x4;    // MFMA C/D frag

__device__ __forceinline__ unsigned short f2b(float f) {
    __hip_bfloat16 h = __float2bfloat16(f);
    return *reinterpret_cast<unsigned short*>(&h);
}

__device__ __forceinline__ bf16x8 cvt8(float4 a, float4 b) {
    bf16x8 r;
    r[0] = (short)f2b(a.x); r[1] = (short)f2b(a.y);
    r[2] = (short)f2b(a.z); r[3] = (short)f2b(a.w);
    r[4] = (short)f2b(b.x); r[5] = (short)f2b(b.y);
    r[6] = (short)f2b(b.z); r[7] = (short)f2b(b.w);
    return r;
}

// ---------------------------------------------------------------------------
// Kernel 1 (VERBATIM, passed): q/k/v = x @ {Wq,Wk,Wv} -> bf16.
// ---------------------------------------------------------------------------
__global__ void qkv_proj(const float* __restrict__ x,
                         const float* __restrict__ Wq,
                         const float* __restrict__ Wk,
                         const float* __restrict__ Wv,
                         unsigned short* __restrict__ qo,
                         unsigned short* __restrict__ ko,
                         unsigned short* __restrict__ vt) {
    __shared__ float xs[16][DIM];
    const int t  = threadIdx.x;
    const int r0 = blockIdx.x * 16;
    const float* W = (blockIdx.y == 0) ? Wq : (blockIdx.y == 1) ? Wk : Wv;

    for (int idx = t; idx < 16 * DIM; idx += 256) {
        xs[idx >> 8][idx & 255] = x[(size_t)(r0 + (idx >> 8)) * DIM + (idx & 255)];
    }
    __syncthreads();

    float acc[16];
#pragma unroll
    for (int r = 0; r < 16; r++) acc[r] = 0.f;

    for (int kk = 0; kk < DIM; kk++) {
        float w = W[(size_t)kk * DIM + t];
#pragma unroll
        for (int r = 0; r < 16; r++) acc[r] += xs[r][kk] * w;  // xs broadcast
    }

    const float scale = 0.17677669529663687f;  // 1/sqrt(32)
    if (blockIdx.y == 0) {
#pragma unroll
        for (int r = 0; r < 16; r++)
            qo[(size_t)(r0 + r) * DIM + t] = f2b(acc[r] * scale);
    } else if (blockIdx.y == 1) {
#pragma unroll
        for (int r = 0; r < 16; r++)
            ko[(size_t)(r0 + r) * DIM + t] = f2b(acc[r]);
    } else {
#pragma unroll
        for (int r = 0; r < 16; r++) {
            int row = r0 + r;
            int bb  = row >> 11;          // row / 2048
            int key = row & 2047;
            vt[((size_t)(bb * 256 + t)) * SEQ + key] = f2b(acc[r]);
        }
    }
}

// ---------------------------------------------------------------------------
// Kernel 2 (REWRITTEN this round): N-split PV + double-buffered register
// prefetch (T14).  K and V fragments go global -> regs -> MFMA directly
// (no LDS round-trip); only P lives in LDS (9.5 KB).
//  - loop unrolled x2 with named A/B register sets (no runtime indexing)
//  - next tile's 12 global_load_dwordx4 issue while current tile computes
//  - 2 barriers/iter (P visible; P reads done)
//  - block remap: h = fid&7 so each XCD keeps one head's K hot in its L2
// ---------------------------------------------------------------------------
__global__ __launch_bounds__(256, 2) void attn_mfma(
        const unsigned short* __restrict__ qb,
        const unsigned short* __restrict__ kb,
        const unsigned short* __restrict__ vtb,
        float* __restrict__ attout) {
    __shared__ __align__(16) unsigned short Ps[64][72];  // shared P tile
    __shared__ float linv[64];

    const int t    = threadIdx.x;
    const int w    = t >> 6;
    const int lane = t & 63;
    const int quad = lane >> 4;
    const int c16  = lane & 15;

    // XCD-friendly decode: consecutive fid -> consecutive XCD -> distinct h
    const int fid  = blockIdx.x;
    const int h    = fid & 7;
    const int b    = (fid >> 3) & 1;
    const int i0b  = (fid >> 4) * 64;        // block q-row base
    const int i0   = i0b + w * 16;           // this wave's q rows (QK phase)

    const size_t qk_head = ((size_t)b * SEQ) * DIM + h * DHEAD;
    const unsigned short* kbase = kb + qk_head;
    const size_t vbase = ((size_t)b * 256) * SEQ;
    const int ncol0 = w * 64;                // this wave's PV column slice

    bf16x8 qf = *(const bf16x8*)&qb[qk_head + (size_t)(i0 + c16) * DIM + quad * 8];

    // per-fragment base pointers (loop-invariant)
    const unsigned short* kp[4];
#pragma unroll
    for (int kt = 0; kt < 4; kt++)
        kp[kt] = kbase + (size_t)(kt * 16 + c16) * DIM + quad * 8;
    const unsigned short* vp[4];
#pragma unroll
    for (int ct = 0; ct < 4; ct++)
        vp[ct] = vtb + vbase + (size_t)(ncol0 + ct * 16 + c16) * SEQ + quad * 8;

    f32x4 acc[4][4];   // [row-tile][col-tile]
#pragma unroll
    for (int rt = 0; rt < 4; rt++)
#pragma unroll
        for (int ct = 0; ct < 4; ct++) acc[rt][ct] = (f32x4){0.f, 0.f, 0.f, 0.f};
    float lrow[4] = {0.f, 0.f, 0.f, 0.f};
    const f32x4 zero = (f32x4){0.f, 0.f, 0.f, 0.f};

#define LOADKV(KD, VD, J0) do {                                               \
    _Pragma("unroll")                                                         \
    for (int kt_ = 0; kt_ < 4; kt_++)                                         \
        KD[kt_] = *(const bf16x8*)(kp[kt_] + (size_t)(J0) * DIM);             \
    _Pragma("unroll")                                                         \
    for (int ct_ = 0; ct_ < 4; ct_++) {                                       \
        VD[ct_]     = *(const bf16x8*)(vp[ct_] + (J0));                       \
        VD[4 + ct_] = *(const bf16x8*)(vp[ct_] + (J0) + 32);                  \
    } } while (0)

#define STEP(KD, VD) do {                                                     \
    f32x4 s_[4];                                                              \
    _Pragma("unroll")                                                         \
    for (int kt_ = 0; kt_ < 4; kt_++)                                         \
        s_[kt_] = __builtin_amdgcn_mfma_f32_16x16x32_bf16(qf, KD[kt_], zero, 0, 0, 0); \
    _Pragma("unroll")                                                         \
    for (int kt_ = 0; kt_ < 4; kt_++) {                                       \
        _Pragma("unroll")                                                     \
        for (int rg_ = 0; rg_ < 4; rg_++) {                                   \
            float p_ = __expf(s_[kt_][rg_]);                                  \
            lrow[rg_] += p_;                                                  \
            Ps[w * 16 + quad * 4 + rg_][kt_ * 16 + c16] = f2b(p_);            \
        }                                                                     \
    }                                                                         \
    __syncthreads();  /* P visible to all waves */                            \
    _Pragma("unroll")                                                         \
    for (int kh_ = 0; kh_ < 2; kh_++) {                                       \
        _Pragma("unroll")                                                     \
        for (int rt_ = 0; rt_ < 4; rt_++) {                                   \
            bf16x8 af_ = *(const bf16x8*)&Ps[rt_ * 16 + c16][kh_ * 32 + quad * 8]; \
            _Pragma("unroll")                                                 \
            for (int ct_ = 0; ct_ < 4; ct_++)                                 \
                acc[rt_][ct_] = __builtin_amdgcn_mfma_f32_16x16x32_bf16(      \
                    af_, VD[kh_ * 4 + ct_], acc[rt_][ct_], 0, 0, 0);          \
        }                                                                     \
    }                                                                         \
    __syncthreads();  /* P reads done before next P writes */                 \
    } while (0)

    bf16x8 kA[4], kB[4], vA[8], vB[8];
    LOADKV(kA, vA, 0);

    for (int jt = 0; jt < SEQ / 64; jt += 2) {
        const int j1 = (jt + 1) * 64;
        LOADKV(kB, vB, j1);            // in flight during STEP(kA)
        STEP(kA, vA);
        if (jt + 2 < SEQ / 64) {
            const int j2 = (jt + 2) * 64;
            LOADKV(kA, vA, j2);        // in flight during STEP(kB)
        }
        STEP(kB, vB);
    }
#undef LOADKV
#undef STEP

    // ---- l broadcast: owner wave writes 1/l for its 16 rows
#pragma unroll
    for (int reg = 0; reg < 4; reg++) {
        float l = lrow[reg];
#pragma unroll
        for (int m = 1; m <= 8; m <<= 1) l += __shfl_xor(l, m, 64);
        if (c16 == 0) linv[w * 16 + quad * 4 + reg] = 1.f / l;
    }
    __syncthreads();

    // ---- write out: rows i0b+rt*16+quad*4+reg, cols h*DIM + ncol0+ct*16+c16
#pragma unroll
    for (int rt = 0; rt < 4; rt++) {
#pragma unroll
        for (int reg = 0; reg < 4; reg++) {
            const int row = i0b + rt * 16 + quad * 4 + reg;
            const float inv = linv[rt * 16 + quad * 4 + reg];
#pragma unroll
            for (int ct = 0; ct < 4; ct++) {
                attout[((size_t)b * SEQ + row) * (size_t)(HEADS * DIM) +
                       h * DIM + ncol0 + ct * 16 + c16] = acc[rt][ct][reg] * inv;
            }
        }
    }
}

// ---------------------------------------------------------------------------
// Kernel 3 (VERBATIM): bf16 transposed weights.
// ---------------------------------------------------------------------------
__global__ void wprep(const float* __restrict__ Wo,
                      const float* __restrict__ Wf1,
                      const float* __restrict__ Wf2,
                      unsigned short* __restrict__ WoT,
                      unsigned short* __restrict__ W1T,
                      unsigned short* __restrict__ W2T) {
    const int tid = blockIdx.x * 256 + threadIdx.x;
    const int stride = gridDim.x * 256;
    const int N1 = 256 * 2048;            // WoT
    const int N2 = N1 + 512 * 256;        // W1T
    const int N3 = N2 + 256 * 512;        // W2T
    for (int i = tid; i < N3; i += stride) {
        if (i < N1) {
            int n = i >> 11, k = i & 2047;
            WoT[i] = f2b(Wo[k * 256 + n]);
        } else if (i < N2) {
            int j = i - N1;
            int n = j >> 8, k = j & 255;
            W1T[j] = f2b(Wf1[k * 512 + n]);
        } else {
            int j = i - N2;
            int n = j >> 9, k = j & 511;
            W2T[j] = f2b(Wf2[k * 256 + n]);
        }
    }
}

// ---------------------------------------------------------------------------
// Kernel 4 (VERBATIM, passed): MFMA wo + residual + LN1 -> bf16 ln1.
// ---------------------------------------------------------------------------
__global__ __launch_bounds__(1024) void wo_ln_mfma(
        const float* __restrict__ attout,        // [4096][2048] fp32
        const unsigned short* __restrict__ WoT,  // [256][2048] bf16
        const float* __restrict__ x,
        const float* __restrict__ gamma1,
        unsigned short* __restrict__ ln1b) {     // [4096][256] bf16
    __shared__ __align__(16) float Cp[4][16][264];   // per-kslice partial C
    __shared__ float ps1[16][16], ps2[16][16];
    __shared__ float mu[16], rsd[16];

    const int t      = threadIdx.x;          // 0..1023
    const int wave   = t >> 6;               // 0..15
    const int kslice = wave >> 2;            // 0..3  -> k0 = kslice*512
    const int wn     = wave & 3;             // col group n0 = wn*64
    const int lane   = t & 63;
    const int quad   = lane >> 4;
    const int c16    = lane & 15;
    const int r0     = blockIdx.x * 16;

    const size_t k0 = (size_t)kslice * 512;
    const float* arow = attout + (size_t)(r0 + c16) * 2048 + k0 + quad * 8;
    const unsigned short* brow = WoT + (size_t)(wn * 64 + c16) * 2048 + k0 + quad * 8;

    f32x4 acc[4];
#pragma unroll
    for (int nt = 0; nt < 4; nt++) acc[nt] = (f32x4){0.f, 0.f, 0.f, 0.f};

    float4 a0 = *(const float4*)(arow);
    float4 a1 = *(const float4*)(arow + 4);
    bf16x8 bb[4];
#pragma unroll
    for (int nt = 0; nt < 4; nt++) bb[nt] = *(const bf16x8*)(brow + nt * 32768);

    for (int kc = 0; kc < 512; kc += 32) {
        const int kn = (kc + 32 < 512) ? kc + 32 : kc;   // last iter: dummy reload
        float4 na0 = *(const float4*)(arow + kn);
        float4 na1 = *(const float4*)(arow + kn + 4);
        bf16x8 nb[4];
#pragma unroll
        for (int nt = 0; nt < 4; nt++) nb[nt] = *(const bf16x8*)(brow + nt * 32768 + kn);

        bf16x8 afg = cvt8(a0, a1);
#pragma unroll
        for (int nt = 0; nt < 4; nt++)
            acc[nt] = __builtin_amdgcn_mfma_f32_16x16x32_bf16(afg, bb[nt], acc[nt], 0, 0, 0);

        a0 = na0; a1 = na1;
#pragma unroll
        for (int nt = 0; nt < 4; nt++) bb[nt] = nb[nt];
    }

#pragma unroll
    for (int reg = 0; reg < 4; reg++) {
        const int row = quad * 4 + reg;
#pragma unroll
        for (int nt = 0; nt < 4; nt++)
            Cp[kslice][row][wn * 64 + nt * 16 + c16] = acc[nt][reg];
    }
    __syncthreads();

#pragma unroll
    for (int p = 0; p < 4; p++) {
        const int idx = t + p * 1024;
        const int row = idx >> 8, col = idx & 255;
        float v = Cp[0][row][col] + Cp[1][row][col] + Cp[2][row][col] + Cp[3][row][col]
                + x[(size_t)(r0 + row) * 256 + col];
        Cp[0][row][col] = v;
    }
    __syncthreads();

    if (t < 256) {
        const int row = t >> 4, seg = t & 15;
        float s = 0.f, s2 = 0.f;
#pragma unroll
        for (int j = 0; j < 16; j++) { float v = Cp[0][row][seg * 16 + j]; s += v; s2 += v * v; }
        ps1[row][seg] = s; ps2[row][seg] = s2;
    }
    __syncthreads();
    if (t < 16) {
        float s = 0.f, s2 = 0.f;
#pragma unroll
        for (int j = 0; j < 16; j++) { s += ps1[t][j]; s2 += ps2[t][j]; }
        float m = s * (1.0f / 256.0f);
        float var = s2 * (1.0f / 256.0f) - m * m;
        mu[t] = m; rsd[t] = rsqrtf(var + EPS);
    }
    __syncthreads();

    {
        const int row = t >> 6;
        const int c4  = (t & 63) * 4;
        float4 cv = *(const float4*)&Cp[0][row][c4];
        float4 g4 = *(const float4*)&gamma1[c4];
        const float m = mu[row], rd = rsd[row];
        bf16x4 o4;
        o4[0] = (short)f2b((cv.x - m) * rd * g4.x);
        o4[1] = (short)f2b((cv.y - m) * rd * g4.y);
        o4[2] = (short)f2b((cv.z - m) * rd * g4.z);
        o4[3] = (short)f2b((cv.w - m) * rd * g4.w);
        *(bf16x4*)&ln1b[(size_t)(r0 + row) * 256 + c4] = o4;
    }
}

// ---------------------------------------------------------------------------
// Kernel 5 (VERBATIM, passed): MFMA bf16 FFN + LN2.
// ---------------------------------------------------------------------------
__global__ __launch_bounds__(1024) void ffn_ln(
        const unsigned short* __restrict__ ln1b,  // [4096][256] bf16
        const unsigned short* __restrict__ W1T,   // [512][256] bf16
        const unsigned short* __restrict__ W2T,   // [256][512] bf16
        const float* __restrict__ gamma2,
        float* __restrict__ out) {
    __shared__ __align__(16) unsigned short xsb[16][264];  // A1 (bf16)
    __shared__ __align__(16) unsigned short hsb[16][520];  // relu(h) (bf16)
    __shared__ __align__(16) float Cs[16][264];            // C (fp32)
    __shared__ float ps1[16][16], ps2[16][16];
    __shared__ float mu[16], rsd[16];

    const int t    = threadIdx.x;         // 0..1023
    const int w    = t >> 6;              // wave 0..15
    const int lane = t & 63;
    const int quad = lane >> 4;
    const int c16  = lane & 15;
    const int r0   = blockIdx.x * 16;
    const f32x4 zero = (f32x4){0.f, 0.f, 0.f, 0.f};

    // stage A: 16 rows x 256 cols bf16 (4 shorts/thread)
    {
        const int row = t >> 6, c4 = (t & 63) * 4;
        *(bf16x4*)&xsb[row][c4] = *(const bf16x4*)&ln1b[(size_t)(r0 + row) * 256 + c4];
    }

    // ---- GEMM1: h = relu(A @ Wf1), wave tile 16x32 ----
    f32x4 acc1[2];
    acc1[0] = zero; acc1[1] = zero;
    const unsigned short* b1 = W1T + (size_t)(w * 32 + c16) * 256 + quad * 8;
    bf16x8 b10 = *(const bf16x8*)(b1);
    bf16x8 b11 = *(const bf16x8*)(b1 + 16 * 256);
    __syncthreads();   // xsb visible

#pragma unroll
    for (int ks = 0; ks < 8; ks++) {
        const int kn = (ks + 1 < 8) ? (ks + 1) * 32 : ks * 32;
        bf16x8 n0 = *(const bf16x8*)(b1 + kn);
        bf16x8 n1 = *(const bf16x8*)(b1 + 16 * 256 + kn);
        bf16x8 af = *(const bf16x8*)&xsb[c16][ks * 32 + quad * 8];
        acc1[0] = __builtin_amdgcn_mfma_f32_16x16x32_bf16(af, b10, acc1[0], 0, 0, 0);
        acc1[1] = __builtin_amdgcn_mfma_f32_16x16x32_bf16(af, b11, acc1[1], 0, 0, 0);
        b10 = n0; b11 = n1;
    }

    // relu + bf16 -> hsb (C/D layout: row=quad*4+reg, col=w*32+nt*16+c16)
#pragma unroll
    for (int nt = 0; nt < 2; nt++)
#pragma unroll
        for (int reg = 0; reg < 4; reg++)
            hsb[quad * 4 + reg][w * 32 + nt * 16 + c16] =
                f2b(fmaxf(acc1[nt][reg], 0.f));
    __syncthreads();

    // ---- GEMM2: C = h @ Wf2, wave tile 16x16 ----
    f32x4 acc2 = zero;
    const unsigned short* b2 = W2T + (size_t)(w * 16 + c16) * 512 + quad * 8;
    bf16x8 b20 = *(const bf16x8*)(b2);
#pragma unroll
    for (int ks = 0; ks < 16; ks++) {
        const int kn = (ks + 1 < 16) ? (ks + 1) * 32 : ks * 32;
        bf16x8 n0 = *(const bf16x8*)(b2 + kn);
        bf16x8 af = *(const bf16x8*)&hsb[c16][ks * 32 + quad * 8];
        acc2 = __builtin_amdgcn_mfma_f32_16x16x32_bf16(af, b20, acc2, 0, 0, 0);
        b20 = n0;
    }
#pragma unroll
    for (int reg = 0; reg < 4; reg++)
        Cs[quad * 4 + reg][w * 16 + c16] = acc2[reg];
    __syncthreads();

    // ---- LN2: 2-stage row reduction over Cs[16][256] ----
    if (t < 256) {
        const int row = t >> 4, seg = t & 15;
        float s = 0.f, s2 = 0.f;
#pragma unroll
        for (int j = 0; j < 16; j++) { float v = Cs[row][seg * 16 + j]; s += v; s2 += v * v; }
        ps1[row][seg] = s; ps2[row][seg] = s2;
    }
    __syncthreads();
    if (t < 16) {
        float s = 0.f, s2 = 0.f;
#pragma unroll
        for (int j = 0; j < 16; j++) { s += ps1[t][j]; s2 += ps2[t][j]; }
        float m = s * (1.0f / DIM);
        float var = s2 * (1.0f / DIM) - m * m;
        mu[t] = m;
        rsd[t] = rsqrtf(var + EPS);
    }
    __syncthreads();

    // write: 1024 threads x float4 = 16 rows x 256 cols
    {
        const int row = t >> 6, c4 = (t & 63) * 4;
        float4 cv = *(const float4*)&Cs[row][c4];
        float4 g4 = *(const float4*)&gamma2[c4];
        const float m = mu[row], rd = rsd[row];
        float4 o;
        o.x = (cv.x - m) * rd * g4.x;
        o.y = (cv.y - m) * rd * g4.y;
        o.z = (cv.z - m) * rd * g4.z;
        o.w = (cv.w - m) * rd * g4.w;
        *(float4*)&out[(size_t)(r0 + row) * DIM + c4] = o;
    }
}

// ---------------------------------------------------------------------------
extern "C" void kernel_launch(void* const* d_in, const int* in_sizes, int n_in,
                              void* d_out, int out_size, void* d_ws, size_t ws_size,
                              hipStream_t stream) {
    const float* x      = (const float*)d_in[0];
    const float* Wq     = (const float*)d_in[1];
    const float* Wk     = (const float*)d_in[2];
    const float* Wv     = (const float*)d_in[3];
    const float* Wo     = (const float*)d_in[4];
    const float* Wf1    = (const float*)d_in[5];
    const float* Wf2    = (const float*)d_in[6];
    const float* gamma1 = (const float*)d_in[7];
    const float* gamma2 = (const float*)d_in[8];
    float* out = (float*)d_out;

    // workspace layout: unchanged.
    char* base = (char*)d_ws;
    unsigned short* qb   = (unsigned short*)(base);              // 2 MB
    unsigned short* kb   = (unsigned short*)(base +  2097152);   // 2 MB
    unsigned short* vtb  = (unsigned short*)(base +  4194304);   // 2 MB
    float* attout        = (float*)         (base +  6291456);   // 32 MB
    unsigned short* ln1b = (unsigned short*)(base + 39845888);   // 2 MB
    unsigned short* W1T  = (unsigned short*)(base + 41943040);   // 256 KB
    unsigned short* W2T  = (unsigned short*)(base + 42205184);   // 256 KB
    unsigned short* WoT  = (unsigned short*)(base + 44040192);   // 1 MB

    wprep<<<64, 256, 0, stream>>>(Wo, Wf1, Wf2, WoT, W1T, W2T);
    qkv_proj<<<dim3(NROWS / 16, 3), 256, 0, stream>>>(x, Wq, Wk, Wv, qb, kb, vtb);
    attn_mfma<<<(SEQ / 64) * HEADS * BATCH, 256, 0, stream>>>(qb, kb, vtb, attout);
    wo_ln_mfma<<<NROWS / 16, 1024, 0, stream>>>(attout, WoT, x, gamma1, ln1b);
    ffn_ln<<<NROWS / 16, 1024, 0, stream>>>(ln1b, W1T, W2T, gamma2, out);
}

// Round 8
// 246.345 us; speedup vs baseline: 1.1396x; 1.1396x over previous
//
#include <hip/hip_runtime.h>
#include <hip/hip_bf16.h>

#define DIM 256
#define HEADS 8
#define DHEAD 32
#define SEQ 2048
#define BATCH 2
#define NROWS (BATCH*SEQ)    // 4096 total rows
#define EPS 1e-5f

typedef __attribute__((ext_vector_type(8))) short bf16x8;   // MFMA A/B frag (4 VGPRs)
typedef __attribute__((ext_vector_type(4))) short bf16x4;   // 4 bf16 (8B)
typedef __attribute__((ext_vector_type(4))) float f32x4;    // MFMA C/D frag

__device__ __forceinline__ unsigned short f2b(float f) {
    __hip_bfloat16 h = __float2bfloat16(f);
    return *reinterpret_cast<unsigned short*>(&h);
}

__device__ __forceinline__ bf16x8 cvt8(float4 a, float4 b) {
    bf16x8 r;
    r[0] = (short)f2b(a.x); r[1] = (short)f2b(a.y);
    r[2] = (short)f2b(a.z); r[3] = (short)f2b(a.w);
    r[4] = (short)f2b(b.x); r[5] = (short)f2b(b.y);
    r[6] = (short)f2b(b.z); r[7] = (short)f2b(b.w);
    return r;
}

// ---------------------------------------------------------------------------
// Kernel 1 (VERBATIM, passed): q/k/v = x @ {Wq,Wk,Wv} -> bf16.
// ---------------------------------------------------------------------------
__global__ void qkv_proj(const float* __restrict__ x,
                         const float* __restrict__ Wq,
                         const float* __restrict__ Wk,
                         const float* __restrict__ Wv,
                         unsigned short* __restrict__ qo,
                         unsigned short* __restrict__ ko,
                         unsigned short* __restrict__ vt) {
    __shared__ float xs[16][DIM];
    const int t  = threadIdx.x;
    const int r0 = blockIdx.x * 16;
    const float* W = (blockIdx.y == 0) ? Wq : (blockIdx.y == 1) ? Wk : Wv;

    for (int idx = t; idx < 16 * DIM; idx += 256) {
        xs[idx >> 8][idx & 255] = x[(size_t)(r0 + (idx >> 8)) * DIM + (idx & 255)];
    }
    __syncthreads();

    float acc[16];
#pragma unroll
    for (int r = 0; r < 16; r++) acc[r] = 0.f;

    for (int kk = 0; kk < DIM; kk++) {
        float w = W[(size_t)kk * DIM + t];
#pragma unroll
        for (int r = 0; r < 16; r++) acc[r] += xs[r][kk] * w;  // xs broadcast
    }

    const float scale = 0.17677669529663687f;  // 1/sqrt(32)
    if (blockIdx.y == 0) {
#pragma unroll
        for (int r = 0; r < 16; r++)
            qo[(size_t)(r0 + r) * DIM + t] = f2b(acc[r] * scale);
    } else if (blockIdx.y == 1) {
#pragma unroll
        for (int r = 0; r < 16; r++)
            ko[(size_t)(r0 + r) * DIM + t] = f2b(acc[r]);
    } else {
#pragma unroll
        for (int r = 0; r < 16; r++) {
            int row = r0 + r;
            int bb  = row >> 11;          // row / 2048
            int key = row & 2047;
            vt[((size_t)(bb * 256 + t)) * SEQ + key] = f2b(acc[r]);
        }
    }
}

// ---------------------------------------------------------------------------
// Kernel 2 (REWRITTEN this round): hybrid flash attention.
//  - round-5 staging: coalesced global->reg->LDS for K and V, T14 1-deep
//    register prefetch (loads for tile jt+1 issue right after the commit
//    barrier, retire under the compute of tile jt).
//  - round-6 N-split PV: wave w computes ALL 64 rows x its PRIVATE 64-col
//    V slice -> reads only 8KB of Vs per iter (M-split read 32KB -> 4x).
//  - P in shared LDS tile [64][68] (stride 68 shorts: 4-way banked reads
//    instead of 8-way at stride 72).
//  - 3 barriers/iter: (A) reads of jt-1 done, (B) stage jt visible,
//    (C) P of jt visible.
// ---------------------------------------------------------------------------
__global__ __launch_bounds__(256, 2) void attn_mfma(
        const unsigned short* __restrict__ qb,
        const unsigned short* __restrict__ kb,
        const unsigned short* __restrict__ vtb,
        float* __restrict__ attout) {
    __shared__ __align__(16) unsigned short Ks[64][40];   // 64 keys x 32 dims
    __shared__ __align__(16) unsigned short Vs[256][80];  // 256 cols x 64 keys
    __shared__ __align__(16) unsigned short Ps[64][68];   // shared P tile
    __shared__ float linv[64];

    const int t    = threadIdx.x;
    const int w    = t >> 6;
    const int lane = t & 63;
    const int quad = lane >> 4;
    const int c16  = lane & 15;

    // XCD-friendly decode: consecutive fid -> consecutive XCD -> distinct h
    const int fid  = blockIdx.x;
    const int h    = fid & 7;
    const int b    = (fid >> 3) & 1;
    const int i0b  = (fid >> 4) * 64;        // block q-row base
    const int i0   = i0b + w * 16;           // this wave's q rows (QK phase)

    const size_t qk_head = ((size_t)b * SEQ) * DIM + h * DHEAD;
    const size_t vbase = ((size_t)b * 256) * SEQ;
    const int ncol0 = w * 64;                // this wave's PV column slice

    bf16x8 qf = *(const bf16x8*)&qb[qk_head + (size_t)(i0 + c16) * DIM + quad * 8];

    // staging thread roles (fixed per thread; fully coalesced)
    const int kkey  = t >> 2, kpart = t & 3;                 // K: 1 frag/thread
    const unsigned short* ksrc = kb + qk_head + (size_t)kkey * DIM + kpart * 8;

    f32x4 acc[4][4];   // [row-tile][col-tile]: rows i0b+rt*16.., cols ncol0+ct*16..
#pragma unroll
    for (int rt = 0; rt < 4; rt++)
#pragma unroll
        for (int ct = 0; ct < 4; ct++) acc[rt][ct] = (f32x4){0.f, 0.f, 0.f, 0.f};
    float lrow[4] = {0.f, 0.f, 0.f, 0.f};
    const f32x4 zero = (f32x4){0.f, 0.f, 0.f, 0.f};

    // prologue: load tile 0 into registers (coalesced)
    bf16x8 kreg = *(const bf16x8*)(ksrc);
    bf16x8 vreg[8];
#pragma unroll
    for (int i = 0; i < 8; i++) {
        int id = t + i * 256;
        int col = id >> 3, part = id & 7;
        vreg[i] = *(const bf16x8*)&vtb[vbase + (size_t)col * SEQ + part * 8];
    }

    for (int jt = 0; jt < SEQ / 64; jt++) {
        __syncthreads();   // (A) all waves done reading Ks/Vs/Ps of jt-1
        // commit registers -> LDS
        *(bf16x8*)&Ks[kkey][kpart * 8] = kreg;
#pragma unroll
        for (int i = 0; i < 8; i++) {
            int id = t + i * 256;
            int col = id >> 3, part = id & 7;
            *(bf16x8*)&Vs[col][part * 8] = vreg[i];
        }
        __syncthreads();   // (B) tile jt visible to all waves

        // issue tile jt+1 global loads; retire under the compute below
        if (jt + 1 < SEQ / 64) {
            const int j1 = (jt + 1) * 64;
            kreg = *(const bf16x8*)(ksrc + (size_t)j1 * DIM);
#pragma unroll
            for (int i = 0; i < 8; i++) {
                int id = t + i * 256;
                int col = id >> 3, part = id & 7;
                vreg[i] = *(const bf16x8*)&vtb[vbase + (size_t)col * SEQ + j1 + part * 8];
            }
        }

        // ---- QK^T (M-split): this wave's 16 rows vs 64 keys, K from LDS
        f32x4 s[4];
#pragma unroll
        for (int kt = 0; kt < 4; kt++) {
            bf16x8 kf = *(const bf16x8*)&Ks[kt * 16 + c16][quad * 8];
            s[kt] = __builtin_amdgcn_mfma_f32_16x16x32_bf16(qf, kf, zero, 0, 0, 0);
        }

        // ---- softmax (no max subtraction), stash P into SHARED tile
#pragma unroll
        for (int kt = 0; kt < 4; kt++) {
#pragma unroll
            for (int reg = 0; reg < 4; reg++) {
                float p = __expf(s[kt][reg]);
                lrow[reg] += p;
                Ps[w * 16 + quad * 4 + reg][kt * 16 + c16] = f2b(p);
            }
        }
        __syncthreads();   // (C) P visible to all waves

        // ---- PV (N-split): all 64 rows x this wave's 64 cols, V from LDS
#pragma unroll
        for (int kh = 0; kh < 2; kh++) {
            bf16x8 vf[4];
#pragma unroll
            for (int ct = 0; ct < 4; ct++)
                vf[ct] = *(const bf16x8*)&Vs[ncol0 + ct * 16 + c16][kh * 32 + quad * 8];
#pragma unroll
            for (int rt = 0; rt < 4; rt++) {
                bf16x8 af = *(const bf16x8*)&Ps[rt * 16 + c16][kh * 32 + quad * 8];
#pragma unroll
                for (int ct = 0; ct < 4; ct++)
                    acc[rt][ct] = __builtin_amdgcn_mfma_f32_16x16x32_bf16(
                        af, vf[ct], acc[rt][ct], 0, 0, 0);
            }
        }
        // next iteration's barrier (A) protects Ps/Vs/Ks reads
    }

    // ---- l broadcast: owner wave writes 1/l for its 16 rows
#pragma unroll
    for (int reg = 0; reg < 4; reg++) {
        float l = lrow[reg];
#pragma unroll
        for (int m = 1; m <= 8; m <<= 1) l += __shfl_xor(l, m, 64);
        if (c16 == 0) linv[w * 16 + quad * 4 + reg] = 1.f / l;
    }
    __syncthreads();

    // ---- write out: rows i0b+rt*16+quad*4+reg, cols h*DIM + ncol0+ct*16+c16
#pragma unroll
    for (int rt = 0; rt < 4; rt++) {
#pragma unroll
        for (int reg = 0; reg < 4; reg++) {
            const int row = i0b + rt * 16 + quad * 4 + reg;
            const float inv = linv[rt * 16 + quad * 4 + reg];
#pragma unroll
            for (int ct = 0; ct < 4; ct++) {
                attout[((size_t)b * SEQ + row) * (size_t)(HEADS * DIM) +
                       h * DIM + ncol0 + ct * 16 + c16] = acc[rt][ct][reg] * inv;
            }
        }
    }
}

// ---------------------------------------------------------------------------
// Kernel 3 (VERBATIM): bf16 transposed weights.
// ---------------------------------------------------------------------------
__global__ void wprep(const float* __restrict__ Wo,
                      const float* __restrict__ Wf1,
                      const float* __restrict__ Wf2,
                      unsigned short* __restrict__ WoT,
                      unsigned short* __restrict__ W1T,
                      unsigned short* __restrict__ W2T) {
    const int tid = blockIdx.x * 256 + threadIdx.x;
    const int stride = gridDim.x * 256;
    const int N1 = 256 * 2048;            // WoT
    const int N2 = N1 + 512 * 256;        // W1T
    const int N3 = N2 + 256 * 512;        // W2T
    for (int i = tid; i < N3; i += stride) {
        if (i < N1) {
            int n = i >> 11, k = i & 2047;
            WoT[i] = f2b(Wo[k * 256 + n]);
        } else if (i < N2) {
            int j = i - N1;
            int n = j >> 8, k = j & 255;
            W1T[j] = f2b(Wf1[k * 512 + n]);
        } else {
            int j = i - N2;
            int n = j >> 9, k = j & 511;
            W2T[j] = f2b(Wf2[k * 256 + n]);
        }
    }
}

// ---------------------------------------------------------------------------
// Kernel 4 (VERBATIM, passed): MFMA wo + residual + LN1 -> bf16 ln1.
// ---------------------------------------------------------------------------
__global__ __launch_bounds__(1024) void wo_ln_mfma(
        const float* __restrict__ attout,        // [4096][2048] fp32
        const unsigned short* __restrict__ WoT,  // [256][2048] bf16
        const float* __restrict__ x,
        const float* __restrict__ gamma1,
        unsigned short* __restrict__ ln1b) {     // [4096][256] bf16
    __shared__ __align__(16) float Cp[4][16][264];   // per-kslice partial C
    __shared__ float ps1[16][16], ps2[16][16];
    __shared__ float mu[16], rsd[16];

    const int t      = threadIdx.x;          // 0..1023
    const int wave   = t >> 6;               // 0..15
    const int kslice = wave >> 2;            // 0..3  -> k0 = kslice*512
    const int wn     = wave & 3;             // col group n0 = wn*64
    const int lane   = t & 63;
    const int quad   = lane >> 4;
    const int c16    = lane & 15;
    const int r0     = blockIdx.x * 16;

    const size_t k0 = (size_t)kslice * 512;
    const float* arow = attout + (size_t)(r0 + c16) * 2048 + k0 + quad * 8;
    const unsigned short* brow = WoT + (size_t)(wn * 64 + c16) * 2048 + k0 + quad * 8;

    f32x4 acc[4];
#pragma unroll
    for (int nt = 0; nt < 4; nt++) acc[nt] = (f32x4){0.f, 0.f, 0.f, 0.f};

    float4 a0 = *(const float4*)(arow);
    float4 a1 = *(const float4*)(arow + 4);
    bf16x8 bb[4];
#pragma unroll
    for (int nt = 0; nt < 4; nt++) bb[nt] = *(const bf16x8*)(brow + nt * 32768);

    for (int kc = 0; kc < 512; kc += 32) {
        const int kn = (kc + 32 < 512) ? kc + 32 : kc;   // last iter: dummy reload
        float4 na0 = *(const float4*)(arow + kn);
        float4 na1 = *(const float4*)(arow + kn + 4);
        bf16x8 nb[4];
#pragma unroll
        for (int nt = 0; nt < 4; nt++) nb[nt] = *(const bf16x8*)(brow + nt * 32768 + kn);

        bf16x8 afg = cvt8(a0, a1);
#pragma unroll
        for (int nt = 0; nt < 4; nt++)
            acc[nt] = __builtin_amdgcn_mfma_f32_16x16x32_bf16(afg, bb[nt], acc[nt], 0, 0, 0);

        a0 = na0; a1 = na1;
#pragma unroll
        for (int nt = 0; nt < 4; nt++) bb[nt] = nb[nt];
    }

#pragma unroll
    for (int reg = 0; reg < 4; reg++) {
        const int row = quad * 4 + reg;
#pragma unroll
        for (int nt = 0; nt < 4; nt++)
            Cp[kslice][row][wn * 64 + nt * 16 + c16] = acc[nt][reg];
    }
    __syncthreads();

#pragma unroll
    for (int p = 0; p < 4; p++) {
        const int idx = t + p * 1024;
        const int row = idx >> 8, col = idx & 255;
        float v = Cp[0][row][col] + Cp[1][row][col] + Cp[2][row][col] + Cp[3][row][col]
                + x[(size_t)(r0 + row) * 256 + col];
        Cp[0][row][col] = v;
    }
    __syncthreads();

    if (t < 256) {
        const int row = t >> 4, seg = t & 15;
        float s = 0.f, s2 = 0.f;
#pragma unroll
        for (int j = 0; j < 16; j++) { float v = Cp[0][row][seg * 16 + j]; s += v; s2 += v * v; }
        ps1[row][seg] = s; ps2[row][seg] = s2;
    }
    __syncthreads();
    if (t < 16) {
        float s = 0.f, s2 = 0.f;
#pragma unroll
        for (int j = 0; j < 16; j++) { s += ps1[t][j]; s2 += ps2[t][j]; }
        float m = s * (1.0f / 256.0f);
        float var = s2 * (1.0f / 256.0f) - m * m;
        mu[t] = m; rsd[t] = rsqrtf(var + EPS);
    }
    __syncthreads();

    {
        const int row = t >> 6;
        const int c4  = (t & 63) * 4;
        float4 cv = *(const float4*)&Cp[0][row][c4];
        float4 g4 = *(const float4*)&gamma1[c4];
        const float m = mu[row], rd = rsd[row];
        bf16x4 o4;
        o4[0] = (short)f2b((cv.x - m) * rd * g4.x);
        o4[1] = (short)f2b((cv.y - m) * rd * g4.y);
        o4[2] = (short)f2b((cv.z - m) * rd * g4.z);
        o4[3] = (short)f2b((cv.w - m) * rd * g4.w);
        *(bf16x4*)&ln1b[(size_t)(r0 + row) * 256 + c4] = o4;
    }
}

// ---------------------------------------------------------------------------
// Kernel 5 (VERBATIM, passed): MFMA bf16 FFN + LN2.
// ---------------------------------------------------------------------------
__global__ __launch_bounds__(1024) void ffn_ln(
        const unsigned short* __restrict__ ln1b,  // [4096][256] bf16
        const unsigned short* __restrict__ W1T,   // [512][256] bf16
        const unsigned short* __restrict__ W2T,   // [256][512] bf16
        const float* __restrict__ gamma2,
        float* __restrict__ out) {
    __shared__ __align__(16) unsigned short xsb[16][264];  // A1 (bf16)
    __shared__ __align__(16) unsigned short hsb[16][520];  // relu(h) (bf16)
    __shared__ __align__(16) float Cs[16][264];            // C (fp32)
    __shared__ float ps1[16][16], ps2[16][16];
    __shared__ float mu[16], rsd[16];

    const int t    = threadIdx.x;         // 0..1023
    const int w    = t >> 6;              // wave 0..15
    const int lane = t & 63;
    const int quad = lane >> 4;
    const int c16  = lane & 15;
    const int r0   = blockIdx.x * 16;
    const f32x4 zero = (f32x4){0.f, 0.f, 0.f, 0.f};

    // stage A: 16 rows x 256 cols bf16 (4 shorts/thread)
    {
        const int row = t >> 6, c4 = (t & 63) * 4;
        *(bf16x4*)&xsb[row][c4] = *(const bf16x4*)&ln1b[(size_t)(r0 + row) * 256 + c4];
    }

    // ---- GEMM1: h = relu(A @ Wf1), wave tile 16x32 ----
    f32x4 acc1[2];
    acc1[0] = zero; acc1[1] = zero;
    const unsigned short* b1 = W1T + (size_t)(w * 32 + c16) * 256 + quad * 8;
    bf16x8 b10 = *(const bf16x8*)(b1);
    bf16x8 b11 = *(const bf16x8*)(b1 + 16 * 256);
    __syncthreads();   // xsb visible

#pragma unroll
    for (int ks = 0; ks < 8; ks++) {
        const int kn = (ks + 1 < 8) ? (ks + 1) * 32 : ks * 32;
        bf16x8 n0 = *(const bf16x8*)(b1 + kn);
        bf16x8 n1 = *(const bf16x8*)(b1 + 16 * 256 + kn);
        bf16x8 af = *(const bf16x8*)&xsb[c16][ks * 32 + quad * 8];
        acc1[0] = __builtin_amdgcn_mfma_f32_16x16x32_bf16(af, b10, acc1[0], 0, 0, 0);
        acc1[1] = __builtin_amdgcn_mfma_f32_16x16x32_bf16(af, b11, acc1[1], 0, 0, 0);
        b10 = n0; b11 = n1;
    }

    // relu + bf16 -> hsb (C/D layout: row=quad*4+reg, col=w*32+nt*16+c16)
#pragma unroll
    for (int nt = 0; nt < 2; nt++)
#pragma unroll
        for (int reg = 0; reg < 4; reg++)
            hsb[quad * 4 + reg][w * 32 + nt * 16 + c16] =
                f2b(fmaxf(acc1[nt][reg], 0.f));
    __syncthreads();

    // ---- GEMM2: C = h @ Wf2, wave tile 16x16 ----
    f32x4 acc2 = zero;
    const unsigned short* b2 = W2T + (size_t)(w * 16 + c16) * 512 + quad * 8;
    bf16x8 b20 = *(const bf16x8*)(b2);
#pragma unroll
    for (int ks = 0; ks < 16; ks++) {
        const int kn = (ks + 1 < 16) ? (ks + 1) * 32 : ks * 32;
        bf16x8 n0 = *(const bf16x8*)(b2 + kn);
        bf16x8 af = *(const bf16x8*)&hsb[c16][ks * 32 + quad * 8];
        acc2 = __builtin_amdgcn_mfma_f32_16x16x32_bf16(af, b20, acc2, 0, 0, 0);
        b20 = n0;
    }
#pragma unroll
    for (int reg = 0; reg < 4; reg++)
        Cs[quad * 4 + reg][w * 16 + c16] = acc2[reg];
    __syncthreads();

    // ---- LN2: 2-stage row reduction over Cs[16][256] ----
    if (t < 256) {
        const int row = t >> 4, seg = t & 15;
        float s = 0.f, s2 = 0.f;
#pragma unroll
        for (int j = 0; j < 16; j++) { float v = Cs[row][seg * 16 + j]; s += v; s2 += v * v; }
        ps1[row][seg] = s; ps2[row][seg] = s2;
    }
    __syncthreads();
    if (t < 16) {
        float s = 0.f, s2 = 0.f;
#pragma unroll
        for (int j = 0; j < 16; j++) { s += ps1[t][j]; s2 += ps2[t][j]; }
        float m = s * (1.0f / DIM);
        float var = s2 * (1.0f / DIM) - m * m;
        mu[t] = m;
        rsd[t] = rsqrtf(var + EPS);
    }
    __syncthreads();

    // write: 1024 threads x float4 = 16 rows x 256 cols
    {
        const int row = t >> 6, c4 = (t & 63) * 4;
        float4 cv = *(const float4*)&Cs[row][c4];
        float4 g4 = *(const float4*)&gamma2[c4];
        const float m = mu[row], rd = rsd[row];
        float4 o;
        o.x = (cv.x - m) * rd * g4.x;
        o.y = (cv.y - m) * rd * g4.y;
        o.z = (cv.z - m) * rd * g4.z;
        o.w = (cv.w - m) * rd * g4.w;
        *(float4*)&out[(size_t)(r0 + row) * DIM + c4] = o;
    }
}

// ---------------------------------------------------------------------------
extern "C" void kernel_launch(void* const* d_in, const int* in_sizes, int n_in,
                              void* d_out, int out_size, void* d_ws, size_t ws_size,
                              hipStream_t stream) {
    const float* x      = (const float*)d_in[0];
    const float* Wq     = (const float*)d_in[1];
    const float* Wk     = (const float*)d_in[2];
    const float* Wv     = (const float*)d_in[3];
    const float* Wo     = (const float*)d_in[4];
    const float* Wf1    = (const float*)d_in[5];
    const float* Wf2    = (const float*)d_in[6];
    const float* gamma1 = (const float*)d_in[7];
    const float* gamma2 = (const float*)d_in[8];
    float* out = (float*)d_out;

    // workspace layout: unchanged.
    char* base = (char*)d_ws;
    unsigned short* qb   = (unsigned short*)(base);              // 2 MB
    unsigned short* kb   = (unsigned short*)(base +  2097152);   // 2 MB
    unsigned short* vtb  = (unsigned short*)(base +  4194304);   // 2 MB
    float* attout        = (float*)         (base +  6291456);   // 32 MB
    unsigned short* ln1b = (unsigned short*)(base + 39845888);   // 2 MB
    unsigned short* W1T  = (unsigned short*)(base + 41943040);   // 256 KB
    unsigned short* W2T  = (unsigned short*)(base + 42205184);   // 256 KB
    unsigned short* WoT  = (unsigned short*)(base + 44040192);   // 1 MB

    wprep<<<64, 256, 0, stream>>>(Wo, Wf1, Wf2, WoT, W1T, W2T);
    qkv_proj<<<dim3(NROWS / 16, 3), 256, 0, stream>>>(x, Wq, Wk, Wv, qb, kb, vtb);
    attn_mfma<<<(SEQ / 64) * HEADS * BATCH, 256, 0, stream>>>(qb, kb, vtb, attout);
    wo_ln_mfma<<<NROWS / 16, 1024, 0, stream>>>(attout, WoT, x, gamma1, ln1b);
    ffn_ln<<<NROWS / 16, 1024, 0, stream>>>(ln1b, W1T, W2T, gamma2, out);
}

// Round 9
// 218.443 us; speedup vs baseline: 1.2852x; 1.1277x over previous
//
#include <hip/hip_runtime.h>
#include <hip/hip_bf16.h>

#define DIM 256
#define HEADS 8
#define DHEAD 32
#define SEQ 2048
#define BATCH 2
#define NROWS (BATCH*SEQ)    // 4096 total rows
#define EPS 1e-5f

typedef __attribute__((ext_vector_type(8))) short bf16x8;   // MFMA A/B frag (4 VGPRs)
typedef __attribute__((ext_vector_type(4))) short bf16x4;   // 4 bf16 (8B)
typedef __attribute__((ext_vector_type(4))) float f32x4;    // MFMA C/D frag

__device__ __forceinline__ unsigned short f2b(float f) {
    __hip_bfloat16 h = __float2bfloat16(f);
    return *reinterpret_cast<unsigned short*>(&h);
}

__device__ __forceinline__ bf16x8 cvt8(float4 a, float4 b) {
    bf16x8 r;
    r[0] = (short)f2b(a.x); r[1] = (short)f2b(a.y);
    r[2] = (short)f2b(a.z); r[3] = (short)f2b(a.w);
    r[4] = (short)f2b(b.x); r[5] = (short)f2b(b.y);
    r[6] = (short)f2b(b.z); r[7] = (short)f2b(b.w);
    return r;
}

// ---------------------------------------------------------------------------
// Kernel 1 (VERBATIM, passed): q/k/v = x @ {Wq,Wk,Wv} -> bf16.
// ---------------------------------------------------------------------------
__global__ void qkv_proj(const float* __restrict__ x,
                         const float* __restrict__ Wq,
                         const float* __restrict__ Wk,
                         const float* __restrict__ Wv,
                         unsigned short* __restrict__ qo,
                         unsigned short* __restrict__ ko,
                         unsigned short* __restrict__ vt) {
    __shared__ float xs[16][DIM];
    const int t  = threadIdx.x;
    const int r0 = blockIdx.x * 16;
    const float* W = (blockIdx.y == 0) ? Wq : (blockIdx.y == 1) ? Wk : Wv;

    for (int idx = t; idx < 16 * DIM; idx += 256) {
        xs[idx >> 8][idx & 255] = x[(size_t)(r0 + (idx >> 8)) * DIM + (idx & 255)];
    }
    __syncthreads();

    float acc[16];
#pragma unroll
    for (int r = 0; r < 16; r++) acc[r] = 0.f;

    for (int kk = 0; kk < DIM; kk++) {
        float w = W[(size_t)kk * DIM + t];
#pragma unroll
        for (int r = 0; r < 16; r++) acc[r] += xs[r][kk] * w;  // xs broadcast
    }

    const float scale = 0.17677669529663687f;  // 1/sqrt(32)
    if (blockIdx.y == 0) {
#pragma unroll
        for (int r = 0; r < 16; r++)
            qo[(size_t)(r0 + r) * DIM + t] = f2b(acc[r] * scale);
    } else if (blockIdx.y == 1) {
#pragma unroll
        for (int r = 0; r < 16; r++)
            ko[(size_t)(r0 + r) * DIM + t] = f2b(acc[r]);
    } else {
#pragma unroll
        for (int r = 0; r < 16; r++) {
            int row = r0 + r;
            int bb  = row >> 11;          // row / 2048
            int key = row & 2047;
            vt[((size_t)(bb * 256 + t)) * SEQ + key] = f2b(acc[r]);
        }
    }
}

// ---------------------------------------------------------------------------
// Kernel 2 (VERBATIM, passed): hybrid flash attention (69 us, round 7).
// ---------------------------------------------------------------------------
__global__ __launch_bounds__(256, 2) void attn_mfma(
        const unsigned short* __restrict__ qb,
        const unsigned short* __restrict__ kb,
        const unsigned short* __restrict__ vtb,
        float* __restrict__ attout) {
    __shared__ __align__(16) unsigned short Ks[64][40];   // 64 keys x 32 dims
    __shared__ __align__(16) unsigned short Vs[256][80];  // 256 cols x 64 keys
    __shared__ __align__(16) unsigned short Ps[64][68];   // shared P tile
    __shared__ float linv[64];

    const int t    = threadIdx.x;
    const int w    = t >> 6;
    const int lane = t & 63;
    const int quad = lane >> 4;
    const int c16  = lane & 15;

    const int fid  = blockIdx.x;
    const int h    = fid & 7;
    const int b    = (fid >> 3) & 1;
    const int i0b  = (fid >> 4) * 64;        // block q-row base
    const int i0   = i0b + w * 16;           // this wave's q rows (QK phase)

    const size_t qk_head = ((size_t)b * SEQ) * DIM + h * DHEAD;
    const size_t vbase = ((size_t)b * 256) * SEQ;
    const int ncol0 = w * 64;                // this wave's PV column slice

    bf16x8 qf = *(const bf16x8*)&qb[qk_head + (size_t)(i0 + c16) * DIM + quad * 8];

    const int kkey  = t >> 2, kpart = t & 3;                 // K: 1 frag/thread
    const unsigned short* ksrc = kb + qk_head + (size_t)kkey * DIM + kpart * 8;

    f32x4 acc[4][4];
#pragma unroll
    for (int rt = 0; rt < 4; rt++)
#pragma unroll
        for (int ct = 0; ct < 4; ct++) acc[rt][ct] = (f32x4){0.f, 0.f, 0.f, 0.f};
    float lrow[4] = {0.f, 0.f, 0.f, 0.f};
    const f32x4 zero = (f32x4){0.f, 0.f, 0.f, 0.f};

    bf16x8 kreg = *(const bf16x8*)(ksrc);
    bf16x8 vreg[8];
#pragma unroll
    for (int i = 0; i < 8; i++) {
        int id = t + i * 256;
        int col = id >> 3, part = id & 7;
        vreg[i] = *(const bf16x8*)&vtb[vbase + (size_t)col * SEQ + part * 8];
    }

    for (int jt = 0; jt < SEQ / 64; jt++) {
        __syncthreads();   // (A) all waves done reading Ks/Vs/Ps of jt-1
        *(bf16x8*)&Ks[kkey][kpart * 8] = kreg;
#pragma unroll
        for (int i = 0; i < 8; i++) {
            int id = t + i * 256;
            int col = id >> 3, part = id & 7;
            *(bf16x8*)&Vs[col][part * 8] = vreg[i];
        }
        __syncthreads();   // (B) tile jt visible to all waves

        if (jt + 1 < SEQ / 64) {
            const int j1 = (jt + 1) * 64;
            kreg = *(const bf16x8*)(ksrc + (size_t)j1 * DIM);
#pragma unroll
            for (int i = 0; i < 8; i++) {
                int id = t + i * 256;
                int col = id >> 3, part = id & 7;
                vreg[i] = *(const bf16x8*)&vtb[vbase + (size_t)col * SEQ + j1 + part * 8];
            }
        }

        f32x4 s[4];
#pragma unroll
        for (int kt = 0; kt < 4; kt++) {
            bf16x8 kf = *(const bf16x8*)&Ks[kt * 16 + c16][quad * 8];
            s[kt] = __builtin_amdgcn_mfma_f32_16x16x32_bf16(qf, kf, zero, 0, 0, 0);
        }

#pragma unroll
        for (int kt = 0; kt < 4; kt++) {
#pragma unroll
            for (int reg = 0; reg < 4; reg++) {
                float p = __expf(s[kt][reg]);
                lrow[reg] += p;
                Ps[w * 16 + quad * 4 + reg][kt * 16 + c16] = f2b(p);
            }
        }
        __syncthreads();   // (C) P visible to all waves

#pragma unroll
        for (int kh = 0; kh < 2; kh++) {
            bf16x8 vf[4];
#pragma unroll
            for (int ct = 0; ct < 4; ct++)
                vf[ct] = *(const bf16x8*)&Vs[ncol0 + ct * 16 + c16][kh * 32 + quad * 8];
#pragma unroll
            for (int rt = 0; rt < 4; rt++) {
                bf16x8 af = *(const bf16x8*)&Ps[rt * 16 + c16][kh * 32 + quad * 8];
#pragma unroll
                for (int ct = 0; ct < 4; ct++)
                    acc[rt][ct] = __builtin_amdgcn_mfma_f32_16x16x32_bf16(
                        af, vf[ct], acc[rt][ct], 0, 0, 0);
            }
        }
    }

#pragma unroll
    for (int reg = 0; reg < 4; reg++) {
        float l = lrow[reg];
#pragma unroll
        for (int m = 1; m <= 8; m <<= 1) l += __shfl_xor(l, m, 64);
        if (c16 == 0) linv[w * 16 + quad * 4 + reg] = 1.f / l;
    }
    __syncthreads();

#pragma unroll
    for (int rt = 0; rt < 4; rt++) {
#pragma unroll
        for (int reg = 0; reg < 4; reg++) {
            const int row = i0b + rt * 16 + quad * 4 + reg;
            const float inv = linv[rt * 16 + quad * 4 + reg];
#pragma unroll
            for (int ct = 0; ct < 4; ct++) {
                attout[((size_t)b * SEQ + row) * (size_t)(HEADS * DIM) +
                       h * DIM + ncol0 + ct * 16 + c16] = acc[rt][ct][reg] * inv;
            }
        }
    }
}

// ---------------------------------------------------------------------------
// Kernel 3 (REWRITTEN this round): MFMA-fragment-packed bf16 weights.
//  Layout: WP[((NT*KSTEPS + KS)*64 + lane)*8 + j] = W[k][n], where
//    n = NT*16 + (lane&15), k = KS*32 + (lane>>4)*8 + j.
//  A wave's B-fragment load becomes ONE contiguous 1KB read (16B/lane),
//  killing the 16-way cache-line scatter of the [n][k] row-major layout
//  (round-6 experiment measured that scatter at ~1.4x kernel cost).
//    WoP: NT<16, KS<64  (256 n x 2048 k)  -> 524288 shorts
//    W1P: NT<32, KS<8   (512 n x  256 k)  -> 131072 shorts
//    W2P: NT<16, KS<16  (256 n x  512 k)  -> 131072 shorts
// ---------------------------------------------------------------------------
__global__ void wprep(const float* __restrict__ Wo,
                      const float* __restrict__ Wf1,
                      const float* __restrict__ Wf2,
                      unsigned short* __restrict__ WoP,
                      unsigned short* __restrict__ W1P,
                      unsigned short* __restrict__ W2P) {
    const int tid = blockIdx.x * 256 + threadIdx.x;
    const int stride = gridDim.x * 256;
    const int N1 = 524288;            // WoP
    const int N2 = N1 + 131072;       // W1P
    const int N3 = N2 + 131072;       // W2P
    for (int i = tid; i < N3; i += stride) {
        if (i < N1) {
            int j = i & 7, l = (i >> 3) & 63, KS = (i >> 9) & 63, NT = i >> 15;
            int n = NT * 16 + (l & 15);
            int k = KS * 32 + ((l >> 4) << 3) + j;
            WoP[i] = f2b(Wo[k * 256 + n]);
        } else if (i < N2) {
            int i2 = i - N1;
            int j = i2 & 7, l = (i2 >> 3) & 63, KS = (i2 >> 9) & 7, NT = i2 >> 12;
            int n = NT * 16 + (l & 15);
            int k = KS * 32 + ((l >> 4) << 3) + j;
            W1P[i2] = f2b(Wf1[k * 512 + n]);
        } else {
            int i2 = i - N2;
            int j = i2 & 7, l = (i2 >> 3) & 63, KS = (i2 >> 9) & 15, NT = i2 >> 13;
            int n = NT * 16 + (l & 15);
            int k = KS * 32 + ((l >> 4) << 3) + j;
            W2P[i2] = f2b(Wf2[k * 256 + n]);
        }
    }
}

// ---------------------------------------------------------------------------
// Kernel 4 (B-addressing CHANGED): MFMA wo + residual + LN1 -> bf16 ln1.
//  B-fragments now from WoP: coalesced 16B/lane loads (was 16-line scatter).
//  NT = wn*4+nt (stride 32768 shorts), KS = kslice*16+ksl (stride 512).
// ---------------------------------------------------------------------------
__global__ __launch_bounds__(1024) void wo_ln_mfma(
        const float* __restrict__ attout,        // [4096][2048] fp32
        const unsigned short* __restrict__ WoP,  // fragment-packed bf16
        const float* __restrict__ x,
        const float* __restrict__ gamma1,
        unsigned short* __restrict__ ln1b) {     // [4096][256] bf16
    __shared__ __align__(16) float Cp[4][16][264];   // per-kslice partial C
    __shared__ float ps1[16][16], ps2[16][16];
    __shared__ float mu[16], rsd[16];

    const int t      = threadIdx.x;          // 0..1023
    const int wave   = t >> 6;               // 0..15
    const int kslice = wave >> 2;            // 0..3  -> k0 = kslice*512
    const int wn     = wave & 3;             // col group n0 = wn*64
    const int lane   = t & 63;
    const int quad   = lane >> 4;
    const int c16    = lane & 15;
    const int r0     = blockIdx.x * 16;

    const size_t k0 = (size_t)kslice * 512;
    const float* arow = attout + (size_t)(r0 + c16) * 2048 + k0 + quad * 8;
    // packed-B fragment base for this wave: NT=wn*4, KS=kslice*16, this lane
    const unsigned short* bfrag = WoP + (size_t)wn * 131072 + (size_t)kslice * 8192
                                      + (size_t)lane * 8;

    f32x4 acc[4];
#pragma unroll
    for (int nt = 0; nt < 4; nt++) acc[nt] = (f32x4){0.f, 0.f, 0.f, 0.f};

    float4 a0 = *(const float4*)(arow);
    float4 a1 = *(const float4*)(arow + 4);
    bf16x8 bb[4];
#pragma unroll
    for (int nt = 0; nt < 4; nt++) bb[nt] = *(const bf16x8*)(bfrag + nt * 32768);

    for (int kc = 0; kc < 512; kc += 32) {
        const int kn  = (kc + 32 < 512) ? kc + 32 : kc;     // last iter: dummy
        const int ksn = kn >> 5;
        float4 na0 = *(const float4*)(arow + kn);
        float4 na1 = *(const float4*)(arow + kn + 4);
        bf16x8 nb[4];
#pragma unroll
        for (int nt = 0; nt < 4; nt++)
            nb[nt] = *(const bf16x8*)(bfrag + nt * 32768 + ksn * 512);

        bf16x8 afg = cvt8(a0, a1);
#pragma unroll
        for (int nt = 0; nt < 4; nt++)
            acc[nt] = __builtin_amdgcn_mfma_f32_16x16x32_bf16(afg, bb[nt], acc[nt], 0, 0, 0);

        a0 = na0; a1 = na1;
#pragma unroll
        for (int nt = 0; nt < 4; nt++) bb[nt] = nb[nt];
    }

#pragma unroll
    for (int reg = 0; reg < 4; reg++) {
        const int row = quad * 4 + reg;
#pragma unroll
        for (int nt = 0; nt < 4; nt++)
            Cp[kslice][row][wn * 64 + nt * 16 + c16] = acc[nt][reg];
    }
    __syncthreads();

#pragma unroll
    for (int p = 0; p < 4; p++) {
        const int idx = t + p * 1024;
        const int row = idx >> 8, col = idx & 255;
        float v = Cp[0][row][col] + Cp[1][row][col] + Cp[2][row][col] + Cp[3][row][col]
                + x[(size_t)(r0 + row) * 256 + col];
        Cp[0][row][col] = v;
    }
    __syncthreads();

    if (t < 256) {
        const int row = t >> 4, seg = t & 15;
        float s = 0.f, s2 = 0.f;
#pragma unroll
        for (int j = 0; j < 16; j++) { float v = Cp[0][row][seg * 16 + j]; s += v; s2 += v * v; }
        ps1[row][seg] = s; ps2[row][seg] = s2;
    }
    __syncthreads();
    if (t < 16) {
        float s = 0.f, s2 = 0.f;
#pragma unroll
        for (int j = 0; j < 16; j++) { s += ps1[t][j]; s2 += ps2[t][j]; }
        float m = s * (1.0f / 256.0f);
        float var = s2 * (1.0f / 256.0f) - m * m;
        mu[t] = m; rsd[t] = rsqrtf(var + EPS);
    }
    __syncthreads();

    {
        const int row = t >> 6;
        const int c4  = (t & 63) * 4;
        float4 cv = *(const float4*)&Cp[0][row][c4];
        float4 g4 = *(const float4*)&gamma1[c4];
        const float m = mu[row], rd = rsd[row];
        bf16x4 o4;
        o4[0] = (short)f2b((cv.x - m) * rd * g4.x);
        o4[1] = (short)f2b((cv.y - m) * rd * g4.y);
        o4[2] = (short)f2b((cv.z - m) * rd * g4.z);
        o4[3] = (short)f2b((cv.w - m) * rd * g4.w);
        *(bf16x4*)&ln1b[(size_t)(r0 + row) * 256 + c4] = o4;
    }
}

// ---------------------------------------------------------------------------
// Kernel 5 (B-addressing CHANGED): MFMA bf16 FFN + LN2, packed weights.
//  GEMM1: NT = w*2+nt (stride 4096 shorts), KS = ks (stride 512).
//  GEMM2: NT = w (stride 8192 shorts), KS = ks (stride 512).
// ---------------------------------------------------------------------------
__global__ __launch_bounds__(1024) void ffn_ln(
        const unsigned short* __restrict__ ln1b,  // [4096][256] bf16
        const unsigned short* __restrict__ W1P,   // fragment-packed bf16
        const unsigned short* __restrict__ W2P,   // fragment-packed bf16
        const float* __restrict__ gamma2,
        float* __restrict__ out) {
    __shared__ __align__(16) unsigned short xsb[16][264];  // A1 (bf16)
    __shared__ __align__(16) unsigned short hsb[16][520];  // relu(h) (bf16)
    __shared__ __align__(16) float Cs[16][264];            // C (fp32)
    __shared__ float ps1[16][16], ps2[16][16];
    __shared__ float mu[16], rsd[16];

    const int t    = threadIdx.x;         // 0..1023
    const int w    = t >> 6;              // wave 0..15
    const int lane = t & 63;
    const int quad = lane >> 4;
    const int c16  = lane & 15;
    const int r0   = blockIdx.x * 16;
    const f32x4 zero = (f32x4){0.f, 0.f, 0.f, 0.f};

    // stage A: 16 rows x 256 cols bf16 (4 shorts/thread)
    {
        const int row = t >> 6, c4 = (t & 63) * 4;
        *(bf16x4*)&xsb[row][c4] = *(const bf16x4*)&ln1b[(size_t)(r0 + row) * 256 + c4];
    }

    // ---- GEMM1: h = relu(A @ Wf1), wave tile 16x32, packed B ----
    f32x4 acc1[2];
    acc1[0] = zero; acc1[1] = zero;
    const unsigned short* b1frag = W1P + (size_t)(w * 2) * 4096 + (size_t)lane * 8;
    bf16x8 b10 = *(const bf16x8*)(b1frag);
    bf16x8 b11 = *(const bf16x8*)(b1frag + 4096);
    __syncthreads();   // xsb visible

#pragma unroll
    for (int ks = 0; ks < 8; ks++) {
        const int ksn = (ks + 1 < 8) ? ks + 1 : ks;
        bf16x8 n0 = *(const bf16x8*)(b1frag + ksn * 512);
        bf16x8 n1 = *(const bf16x8*)(b1frag + 4096 + ksn * 512);
        bf16x8 af = *(const bf16x8*)&xsb[c16][ks * 32 + quad * 8];
        acc1[0] = __builtin_amdgcn_mfma_f32_16x16x32_bf16(af, b10, acc1[0], 0, 0, 0);
        acc1[1] = __builtin_amdgcn_mfma_f32_16x16x32_bf16(af, b11, acc1[1], 0, 0, 0);
        b10 = n0; b11 = n1;
    }

    // relu + bf16 -> hsb (C/D layout: row=quad*4+reg, col=w*32+nt*16+c16)
#pragma unroll
    for (int nt = 0; nt < 2; nt++)
#pragma unroll
        for (int reg = 0; reg < 4; reg++)
            hsb[quad * 4 + reg][w * 32 + nt * 16 + c16] =
                f2b(fmaxf(acc1[nt][reg], 0.f));
    __syncthreads();

    // ---- GEMM2: C = h @ Wf2, wave tile 16x16, packed B ----
    f32x4 acc2 = zero;
    const unsigned short* b2frag = W2P + (size_t)w * 8192 + (size_t)lane * 8;
    bf16x8 b20 = *(const bf16x8*)(b2frag);
#pragma unroll
    for (int ks = 0; ks < 16; ks++) {
        const int ksn = (ks + 1 < 16) ? ks + 1 : ks;
        bf16x8 n0 = *(const bf16x8*)(b2frag + ksn * 512);
        bf16x8 af = *(const bf16x8*)&hsb[c16][ks * 32 + quad * 8];
        acc2 = __builtin_amdgcn_mfma_f32_16x16x32_bf16(af, b20, acc2, 0, 0, 0);
        b20 = n0;
    }
#pragma unroll
    for (int reg = 0; reg < 4; reg++)
        Cs[quad * 4 + reg][w * 16 + c16] = acc2[reg];
    __syncthreads();

    // ---- LN2: 2-stage row reduction over Cs[16][256] ----
    if (t < 256) {
        const int row = t >> 4, seg = t & 15;
        float s = 0.f, s2 = 0.f;
#pragma unroll
        for (int j = 0; j < 16; j++) { float v = Cs[row][seg * 16 + j]; s += v; s2 += v * v; }
        ps1[row][seg] = s; ps2[row][seg] = s2;
    }
    __syncthreads();
    if (t < 16) {
        float s = 0.f, s2 = 0.f;
#pragma unroll
        for (int j = 0; j < 16; j++) { s += ps1[t][j]; s2 += ps2[t][j]; }
        float m = s * (1.0f / DIM);
        float var = s2 * (1.0f / DIM) - m * m;
        mu[t] = m;
        rsd[t] = rsqrtf(var + EPS);
    }
    __syncthreads();

    // write: 1024 threads x float4 = 16 rows x 256 cols
    {
        const int row = t >> 6, c4 = (t & 63) * 4;
        float4 cv = *(const float4*)&Cs[row][c4];
        float4 g4 = *(const float4*)&gamma2[c4];
        const float m = mu[row], rd = rsd[row];
        float4 o;
        o.x = (cv.x - m) * rd * g4.x;
        o.y = (cv.y - m) * rd * g4.y;
        o.z = (cv.z - m) * rd * g4.z;
        o.w = (cv.w - m) * rd * g4.w;
        *(float4*)&out[(size_t)(r0 + row) * DIM + c4] = o;
    }
}

// ---------------------------------------------------------------------------
extern "C" void kernel_launch(void* const* d_in, const int* in_sizes, int n_in,
                              void* d_out, int out_size, void* d_ws, size_t ws_size,
                              hipStream_t stream) {
    const float* x      = (const float*)d_in[0];
    const float* Wq     = (const float*)d_in[1];
    const float* Wk     = (const float*)d_in[2];
    const float* Wv     = (const float*)d_in[3];
    const float* Wo     = (const float*)d_in[4];
    const float* Wf1    = (const float*)d_in[5];
    const float* Wf2    = (const float*)d_in[6];
    const float* gamma1 = (const float*)d_in[7];
    const float* gamma2 = (const float*)d_in[8];
    float* out = (float*)d_out;

    // workspace layout: unchanged offsets (packed weights reuse old slots).
    char* base = (char*)d_ws;
    unsigned short* qb   = (unsigned short*)(base);              // 2 MB
    unsigned short* kb   = (unsigned short*)(base +  2097152);   // 2 MB
    unsigned short* vtb  = (unsigned short*)(base +  4194304);   // 2 MB
    float* attout        = (float*)         (base +  6291456);   // 32 MB
    unsigned short* ln1b = (unsigned short*)(base + 39845888);   // 2 MB
    unsigned short* W1P  = (unsigned short*)(base + 41943040);   // 256 KB
    unsigned short* W2P  = (unsigned short*)(base + 42205184);   // 256 KB
    unsigned short* WoP  = (unsigned short*)(base + 44040192);   // 1 MB

    wprep<<<64, 256, 0, stream>>>(Wo, Wf1, Wf2, WoP, W1P, W2P);
    qkv_proj<<<dim3(NROWS / 16, 3), 256, 0, stream>>>(x, Wq, Wk, Wv, qb, kb, vtb);
    attn_mfma<<<(SEQ / 64) * HEADS * BATCH, 256, 0, stream>>>(qb, kb, vtb, attout);
    wo_ln_mfma<<<NROWS / 16, 1024, 0, stream>>>(attout, WoP, x, gamma1, ln1b);
    ffn_ln<<<NROWS / 16, 1024, 0, stream>>>(ln1b, W1P, W2P, gamma2, out);
}

// Round 10
// 194.281 us; speedup vs baseline: 1.4450x; 1.1244x over previous
//
#include <hip/hip_runtime.h>
#include <hip/hip_bf16.h>

#define DIM 256
#define HEADS 8
#define DHEAD 32
#define SEQ 2048
#define BATCH 2
#define NROWS (BATCH*SEQ)    // 4096 total rows
#define EPS 1e-5f

typedef __attribute__((ext_vector_type(8))) short bf16x8;   // MFMA A/B frag (4 VGPRs)
typedef __attribute__((ext_vector_type(4))) short bf16x4;   // 4 bf16 (8B)
typedef __attribute__((ext_vector_type(4))) float f32x4;    // MFMA C/D frag

__device__ __forceinline__ unsigned short f2b(float f) {
    __hip_bfloat16 h = __float2bfloat16(f);
    return *reinterpret_cast<unsigned short*>(&h);
}

__device__ __forceinline__ bf16x8 cvt8(float4 a, float4 b) {
    bf16x8 r;
    r[0] = (short)f2b(a.x); r[1] = (short)f2b(a.y);
    r[2] = (short)f2b(a.z); r[3] = (short)f2b(a.w);
    r[4] = (short)f2b(b.x); r[5] = (short)f2b(b.y);
    r[6] = (short)f2b(b.z); r[7] = (short)f2b(b.w);
    return r;
}

// ---------------------------------------------------------------------------
// Kernel 1 (REWRITTEN this round): MFMA qkv projection, packed weights.
//  16 rows/block, 1024 threads (16 waves).  Wave w owns n-tile w (cols
//  w*16..w*16+15) of ALL THREE projections: 3 acc, 24 MFMAs, K=256.
//  A (x rows) staged once through LDS as bf16 (coalesced float4 reads).
//  B from fragment-packed WqP/WkP/WvP: one contiguous 1KB read per frag.
// ---------------------------------------------------------------------------
__global__ __launch_bounds__(1024) void qkv_mfma(
        const float* __restrict__ x,
        const unsigned short* __restrict__ WqP,
        const unsigned short* __restrict__ WkP,
        const unsigned short* __restrict__ WvP,
        unsigned short* __restrict__ qo,
        unsigned short* __restrict__ ko,
        unsigned short* __restrict__ vt) {
    __shared__ __align__(16) unsigned short xsb[16][264];

    const int t    = threadIdx.x;         // 0..1023
    const int w    = t >> 6;              // wave 0..15 = n-tile
    const int lane = t & 63;
    const int quad = lane >> 4;
    const int c16  = lane & 15;
    const int r0   = blockIdx.x * 16;
    const f32x4 zero = (f32x4){0.f, 0.f, 0.f, 0.f};

    // stage A: 16 rows x 256 cols fp32 -> bf16 LDS (1024 x float4)
    {
        const int row = t >> 6, c4 = (t & 63) * 4;
        float4 v4 = *(const float4*)&x[(size_t)(r0 + row) * 256 + c4];
        bf16x4 b4;
        b4[0] = (short)f2b(v4.x); b4[1] = (short)f2b(v4.y);
        b4[2] = (short)f2b(v4.z); b4[3] = (short)f2b(v4.w);
        *(bf16x4*)&xsb[row][c4] = b4;
    }

    f32x4 aq = zero, ak = zero, av = zero;
    const unsigned short* bq = WqP + (size_t)w * 4096 + (size_t)lane * 8;
    const unsigned short* bk = WkP + (size_t)w * 4096 + (size_t)lane * 8;
    const unsigned short* bv = WvP + (size_t)w * 4096 + (size_t)lane * 8;

    bf16x8 q0 = *(const bf16x8*)(bq);
    bf16x8 k0 = *(const bf16x8*)(bk);
    bf16x8 v0 = *(const bf16x8*)(bv);
    __syncthreads();   // xsb visible

#pragma unroll
    for (int ks = 0; ks < 8; ks++) {
        const int ksn = (ks + 1 < 8) ? ks + 1 : ks;     // last iter: dummy
        bf16x8 qn = *(const bf16x8*)(bq + ksn * 512);
        bf16x8 kn = *(const bf16x8*)(bk + ksn * 512);
        bf16x8 vn = *(const bf16x8*)(bv + ksn * 512);
        bf16x8 af = *(const bf16x8*)&xsb[c16][ks * 32 + quad * 8];
        aq = __builtin_amdgcn_mfma_f32_16x16x32_bf16(af, q0, aq, 0, 0, 0);
        ak = __builtin_amdgcn_mfma_f32_16x16x32_bf16(af, k0, ak, 0, 0, 0);
        av = __builtin_amdgcn_mfma_f32_16x16x32_bf16(af, v0, av, 0, 0, 0);
        q0 = qn; k0 = kn; v0 = vn;
    }

    // epilogue (C/D layout: row=quad*4+reg, col=w*16+c16)
    const float scale = 0.17677669529663687f;  // 1/sqrt(32)
    const int col = w * 16 + c16;
#pragma unroll
    for (int reg = 0; reg < 4; reg++) {
        const int row = r0 + quad * 4 + reg;
        qo[(size_t)row * 256 + col] = f2b(aq[reg] * scale);
        ko[(size_t)row * 256 + col] = f2b(ak[reg]);
    }
    {   // v transposed: vt[(bb*256 + col)*2048 + key], 4 consecutive keys
        const int bb   = r0 >> 11;
        const int key0 = (r0 & 2047) + quad * 4;
        bf16x4 v4;
        v4[0] = (short)f2b(av[0]); v4[1] = (short)f2b(av[1]);
        v4[2] = (short)f2b(av[2]); v4[3] = (short)f2b(av[3]);
        *(bf16x4*)&vt[((size_t)(bb * 256 + col)) * 2048 + key0] = v4;
    }
}

// ---------------------------------------------------------------------------
// Kernel 2 (VERBATIM, passed): hybrid flash attention (69 us, round 7).
// ---------------------------------------------------------------------------
__global__ __launch_bounds__(256, 2) void attn_mfma(
        const unsigned short* __restrict__ qb,
        const unsigned short* __restrict__ kb,
        const unsigned short* __restrict__ vtb,
        float* __restrict__ attout) {
    __shared__ __align__(16) unsigned short Ks[64][40];   // 64 keys x 32 dims
    __shared__ __align__(16) unsigned short Vs[256][80];  // 256 cols x 64 keys
    __shared__ __align__(16) unsigned short Ps[64][68];   // shared P tile
    __shared__ float linv[64];

    const int t    = threadIdx.x;
    const int w    = t >> 6;
    const int lane = t & 63;
    const int quad = lane >> 4;
    const int c16  = lane & 15;

    const int fid  = blockIdx.x;
    const int h    = fid & 7;
    const int b    = (fid >> 3) & 1;
    const int i0b  = (fid >> 4) * 64;        // block q-row base
    const int i0   = i0b + w * 16;           // this wave's q rows (QK phase)

    const size_t qk_head = ((size_t)b * SEQ) * DIM + h * DHEAD;
    const size_t vbase = ((size_t)b * 256) * SEQ;
    const int ncol0 = w * 64;                // this wave's PV column slice

    bf16x8 qf = *(const bf16x8*)&qb[qk_head + (size_t)(i0 + c16) * DIM + quad * 8];

    const int kkey  = t >> 2, kpart = t & 3;                 // K: 1 frag/thread
    const unsigned short* ksrc = kb + qk_head + (size_t)kkey * DIM + kpart * 8;

    f32x4 acc[4][4];
#pragma unroll
    for (int rt = 0; rt < 4; rt++)
#pragma unroll
        for (int ct = 0; ct < 4; ct++) acc[rt][ct] = (f32x4){0.f, 0.f, 0.f, 0.f};
    float lrow[4] = {0.f, 0.f, 0.f, 0.f};
    const f32x4 zero = (f32x4){0.f, 0.f, 0.f, 0.f};

    bf16x8 kreg = *(const bf16x8*)(ksrc);
    bf16x8 vreg[8];
#pragma unroll
    for (int i = 0; i < 8; i++) {
        int id = t + i * 256;
        int col = id >> 3, part = id & 7;
        vreg[i] = *(const bf16x8*)&vtb[vbase + (size_t)col * SEQ + part * 8];
    }

    for (int jt = 0; jt < SEQ / 64; jt++) {
        __syncthreads();   // (A) all waves done reading Ks/Vs/Ps of jt-1
        *(bf16x8*)&Ks[kkey][kpart * 8] = kreg;
#pragma unroll
        for (int i = 0; i < 8; i++) {
            int id = t + i * 256;
            int col = id >> 3, part = id & 7;
            *(bf16x8*)&Vs[col][part * 8] = vreg[i];
        }
        __syncthreads();   // (B) tile jt visible to all waves

        if (jt + 1 < SEQ / 64) {
            const int j1 = (jt + 1) * 64;
            kreg = *(const bf16x8*)(ksrc + (size_t)j1 * DIM);
#pragma unroll
            for (int i = 0; i < 8; i++) {
                int id = t + i * 256;
                int col = id >> 3, part = id & 7;
                vreg[i] = *(const bf16x8*)&vtb[vbase + (size_t)col * SEQ + j1 + part * 8];
            }
        }

        f32x4 s[4];
#pragma unroll
        for (int kt = 0; kt < 4; kt++) {
            bf16x8 kf = *(const bf16x8*)&Ks[kt * 16 + c16][quad * 8];
            s[kt] = __builtin_amdgcn_mfma_f32_16x16x32_bf16(qf, kf, zero, 0, 0, 0);
        }

#pragma unroll
        for (int kt = 0; kt < 4; kt++) {
#pragma unroll
            for (int reg = 0; reg < 4; reg++) {
                float p = __expf(s[kt][reg]);
                lrow[reg] += p;
                Ps[w * 16 + quad * 4 + reg][kt * 16 + c16] = f2b(p);
            }
        }
        __syncthreads();   // (C) P visible to all waves

#pragma unroll
        for (int kh = 0; kh < 2; kh++) {
            bf16x8 vf[4];
#pragma unroll
            for (int ct = 0; ct < 4; ct++)
                vf[ct] = *(const bf16x8*)&Vs[ncol0 + ct * 16 + c16][kh * 32 + quad * 8];
#pragma unroll
            for (int rt = 0; rt < 4; rt++) {
                bf16x8 af = *(const bf16x8*)&Ps[rt * 16 + c16][kh * 32 + quad * 8];
#pragma unroll
                for (int ct = 0; ct < 4; ct++)
                    acc[rt][ct] = __builtin_amdgcn_mfma_f32_16x16x32_bf16(
                        af, vf[ct], acc[rt][ct], 0, 0, 0);
            }
        }
    }

#pragma unroll
    for (int reg = 0; reg < 4; reg++) {
        float l = lrow[reg];
#pragma unroll
        for (int m = 1; m <= 8; m <<= 1) l += __shfl_xor(l, m, 64);
        if (c16 == 0) linv[w * 16 + quad * 4 + reg] = 1.f / l;
    }
    __syncthreads();

#pragma unroll
    for (int rt = 0; rt < 4; rt++) {
#pragma unroll
        for (int reg = 0; reg < 4; reg++) {
            const int row = i0b + rt * 16 + quad * 4 + reg;
            const float inv = linv[rt * 16 + quad * 4 + reg];
#pragma unroll
            for (int ct = 0; ct < 4; ct++) {
                attout[((size_t)b * SEQ + row) * (size_t)(HEADS * DIM) +
                       h * DIM + ncol0 + ct * 16 + c16] = acc[rt][ct][reg] * inv;
            }
        }
    }
}

// ---------------------------------------------------------------------------
// Kernel 3 (EXTENDED this round): MFMA-fragment-packed bf16 weights.
//  WP[((NT*KSTEPS + KS)*64 + lane)*8 + j] = W[k][n],
//    n = NT*16 + (lane&15), k = KS*32 + (lane>>4)*8 + j.
//    WoP: NT<16, KS<64  -> 524288 shorts
//    W1P: NT<32, KS<8   -> 131072 shorts
//    W2P: NT<16, KS<16  -> 131072 shorts
//    WqP/WkP/WvP: NT<16, KS<8 -> 65536 shorts each
// ---------------------------------------------------------------------------
__global__ void wprep(const float* __restrict__ Wo,
                      const float* __restrict__ Wf1,
                      const float* __restrict__ Wf2,
                      const float* __restrict__ Wq,
                      const float* __restrict__ Wk,
                      const float* __restrict__ Wv,
                      unsigned short* __restrict__ WoP,
                      unsigned short* __restrict__ W1P,
                      unsigned short* __restrict__ W2P,
                      unsigned short* __restrict__ WqP,
                      unsigned short* __restrict__ WkP,
                      unsigned short* __restrict__ WvP) {
    const int tid = blockIdx.x * 256 + threadIdx.x;
    const int stride = gridDim.x * 256;
    const int N1 = 524288;            // WoP
    const int N2 = N1 + 131072;       // W1P
    const int N3 = N2 + 131072;       // W2P
    const int N4 = N3 + 65536;        // WqP
    const int N5 = N4 + 65536;        // WkP
    const int N6 = N5 + 65536;        // WvP
    for (int i = tid; i < N6; i += stride) {
        if (i < N1) {
            int j = i & 7, l = (i >> 3) & 63, KS = (i >> 9) & 63, NT = i >> 15;
            int n = NT * 16 + (l & 15);
            int k = KS * 32 + ((l >> 4) << 3) + j;
            WoP[i] = f2b(Wo[k * 256 + n]);
        } else if (i < N2) {
            int i2 = i - N1;
            int j = i2 & 7, l = (i2 >> 3) & 63, KS = (i2 >> 9) & 7, NT = i2 >> 12;
            int n = NT * 16 + (l & 15);
            int k = KS * 32 + ((l >> 4) << 3) + j;
            W1P[i2] = f2b(Wf1[k * 512 + n]);
        } else if (i < N3) {
            int i2 = i - N2;
            int j = i2 & 7, l = (i2 >> 3) & 63, KS = (i2 >> 9) & 15, NT = i2 >> 13;
            int n = NT * 16 + (l & 15);
            int k = KS * 32 + ((l >> 4) << 3) + j;
            W2P[i2] = f2b(Wf2[k * 256 + n]);
        } else {
            int i2 = (i - N3) & 65535;
            int j = i2 & 7, l = (i2 >> 3) & 63, KS = (i2 >> 9) & 7, NT = i2 >> 12;
            int n = NT * 16 + (l & 15);
            int k = KS * 32 + ((l >> 4) << 3) + j;
            float v = (i < N4) ? Wq[k * 256 + n] : (i < N5) ? Wk[k * 256 + n]
                                                            : Wv[k * 256 + n];
            unsigned short* dst = (i < N4) ? WqP : (i < N5) ? WkP : WvP;
            dst[i2] = f2b(v);
        }
    }
}

// ---------------------------------------------------------------------------
// Kernel 4 (VERBATIM, passed): MFMA wo + residual + LN1 -> bf16 ln1.
// ---------------------------------------------------------------------------
__global__ __launch_bounds__(1024) void wo_ln_mfma(
        const float* __restrict__ attout,        // [4096][2048] fp32
        const unsigned short* __restrict__ WoP,  // fragment-packed bf16
        const float* __restrict__ x,
        const float* __restrict__ gamma1,
        unsigned short* __restrict__ ln1b) {     // [4096][256] bf16
    __shared__ __align__(16) float Cp[4][16][264];   // per-kslice partial C
    __shared__ float ps1[16][16], ps2[16][16];
    __shared__ float mu[16], rsd[16];

    const int t      = threadIdx.x;          // 0..1023
    const int wave   = t >> 6;               // 0..15
    const int kslice = wave >> 2;            // 0..3  -> k0 = kslice*512
    const int wn     = wave & 3;             // col group n0 = wn*64
    const int lane   = t & 63;
    const int quad   = lane >> 4;
    const int c16    = lane & 15;
    const int r0     = blockIdx.x * 16;

    const size_t k0 = (size_t)kslice * 512;
    const float* arow = attout + (size_t)(r0 + c16) * 2048 + k0 + quad * 8;
    const unsigned short* bfrag = WoP + (size_t)wn * 131072 + (size_t)kslice * 8192
                                      + (size_t)lane * 8;

    f32x4 acc[4];
#pragma unroll
    for (int nt = 0; nt < 4; nt++) acc[nt] = (f32x4){0.f, 0.f, 0.f, 0.f};

    float4 a0 = *(const float4*)(arow);
    float4 a1 = *(const float4*)(arow + 4);
    bf16x8 bb[4];
#pragma unroll
    for (int nt = 0; nt < 4; nt++) bb[nt] = *(const bf16x8*)(bfrag + nt * 32768);

    for (int kc = 0; kc < 512; kc += 32) {
        const int kn  = (kc + 32 < 512) ? kc + 32 : kc;     // last iter: dummy
        const int ksn = kn >> 5;
        float4 na0 = *(const float4*)(arow + kn);
        float4 na1 = *(const float4*)(arow + kn + 4);
        bf16x8 nb[4];
#pragma unroll
        for (int nt = 0; nt < 4; nt++)
            nb[nt] = *(const bf16x8*)(bfrag + nt * 32768 + ksn * 512);

        bf16x8 afg = cvt8(a0, a1);
#pragma unroll
        for (int nt = 0; nt < 4; nt++)
            acc[nt] = __builtin_amdgcn_mfma_f32_16x16x32_bf16(afg, bb[nt], acc[nt], 0, 0, 0);

        a0 = na0; a1 = na1;
#pragma unroll
        for (int nt = 0; nt < 4; nt++) bb[nt] = nb[nt];
    }

#pragma unroll
    for (int reg = 0; reg < 4; reg++) {
        const int row = quad * 4 + reg;
#pragma unroll
        for (int nt = 0; nt < 4; nt++)
            Cp[kslice][row][wn * 64 + nt * 16 + c16] = acc[nt][reg];
    }
    __syncthreads();

#pragma unroll
    for (int p = 0; p < 4; p++) {
        const int idx = t + p * 1024;
        const int row = idx >> 8, col = idx & 255;
        float v = Cp[0][row][col] + Cp[1][row][col] + Cp[2][row][col] + Cp[3][row][col]
                + x[(size_t)(r0 + row) * 256 + col];
        Cp[0][row][col] = v;
    }
    __syncthreads();

    if (t < 256) {
        const int row = t >> 4, seg = t & 15;
        float s = 0.f, s2 = 0.f;
#pragma unroll
        for (int j = 0; j < 16; j++) { float v = Cp[0][row][seg * 16 + j]; s += v; s2 += v * v; }
        ps1[row][seg] = s; ps2[row][seg] = s2;
    }
    __syncthreads();
    if (t < 16) {
        float s = 0.f, s2 = 0.f;
#pragma unroll
        for (int j = 0; j < 16; j++) { s += ps1[t][j]; s2 += ps2[t][j]; }
        float m = s * (1.0f / 256.0f);
        float var = s2 * (1.0f / 256.0f) - m * m;
        mu[t] = m; rsd[t] = rsqrtf(var + EPS);
    }
    __syncthreads();

    {
        const int row = t >> 6;
        const int c4  = (t & 63) * 4;
        float4 cv = *(const float4*)&Cp[0][row][c4];
        float4 g4 = *(const float4*)&gamma1[c4];
        const float m = mu[row], rd = rsd[row];
        bf16x4 o4;
        o4[0] = (short)f2b((cv.x - m) * rd * g4.x);
        o4[1] = (short)f2b((cv.y - m) * rd * g4.y);
        o4[2] = (short)f2b((cv.z - m) * rd * g4.z);
        o4[3] = (short)f2b((cv.w - m) * rd * g4.w);
        *(bf16x4*)&ln1b[(size_t)(r0 + row) * 256 + c4] = o4;
    }
}

// ---------------------------------------------------------------------------
// Kernel 5 (VERBATIM, passed): MFMA bf16 FFN + LN2, packed weights.
// ---------------------------------------------------------------------------
__global__ __launch_bounds__(1024) void ffn_ln(
        const unsigned short* __restrict__ ln1b,  // [4096][256] bf16
        const unsigned short* __restrict__ W1P,   // fragment-packed bf16
        const unsigned short* __restrict__ W2P,   // fragment-packed bf16
        const float* __restrict__ gamma2,
        float* __restrict__ out) {
    __shared__ __align__(16) unsigned short xsb[16][264];  // A1 (bf16)
    __shared__ __align__(16) unsigned short hsb[16][520];  // relu(h) (bf16)
    __shared__ __align__(16) float Cs[16][264];            // C (fp32)
    __shared__ float ps1[16][16], ps2[16][16];
    __shared__ float mu[16], rsd[16];

    const int t    = threadIdx.x;         // 0..1023
    const int w    = t >> 6;              // wave 0..15
    const int lane = t & 63;
    const int quad = lane >> 4;
    const int c16  = lane & 15;
    const int r0   = blockIdx.x * 16;
    const f32x4 zero = (f32x4){0.f, 0.f, 0.f, 0.f};

    // stage A: 16 rows x 256 cols bf16 (4 shorts/thread)
    {
        const int row = t >> 6, c4 = (t & 63) * 4;
        *(bf16x4*)&xsb[row][c4] = *(const bf16x4*)&ln1b[(size_t)(r0 + row) * 256 + c4];
    }

    // ---- GEMM1: h = relu(A @ Wf1), wave tile 16x32, packed B ----
    f32x4 acc1[2];
    acc1[0] = zero; acc1[1] = zero;
    const unsigned short* b1frag = W1P + (size_t)(w * 2) * 4096 + (size_t)lane * 8;
    bf16x8 b10 = *(const bf16x8*)(b1frag);
    bf16x8 b11 = *(const bf16x8*)(b1frag + 4096);
    __syncthreads();   // xsb visible

#pragma unroll
    for (int ks = 0; ks < 8; ks++) {
        const int ksn = (ks + 1 < 8) ? ks + 1 : ks;
        bf16x8 n0 = *(const bf16x8*)(b1frag + ksn * 512);
        bf16x8 n1 = *(const bf16x8*)(b1frag + 4096 + ksn * 512);
        bf16x8 af = *(const bf16x8*)&xsb[c16][ks * 32 + quad * 8];
        acc1[0] = __builtin_amdgcn_mfma_f32_16x16x32_bf16(af, b10, acc1[0], 0, 0, 0);
        acc1[1] = __builtin_amdgcn_mfma_f32_16x16x32_bf16(af, b11, acc1[1], 0, 0, 0);
        b10 = n0; b11 = n1;
    }

    // relu + bf16 -> hsb (C/D layout: row=quad*4+reg, col=w*32+nt*16+c16)
#pragma unroll
    for (int nt = 0; nt < 2; nt++)
#pragma unroll
        for (int reg = 0; reg < 4; reg++)
            hsb[quad * 4 + reg][w * 32 + nt * 16 + c16] =
                f2b(fmaxf(acc1[nt][reg], 0.f));
    __syncthreads();

    // ---- GEMM2: C = h @ Wf2, wave tile 16x16, packed B ----
    f32x4 acc2 = zero;
    const unsigned short* b2frag = W2P + (size_t)w * 8192 + (size_t)lane * 8;
    bf16x8 b20 = *(const bf16x8*)(b2frag);
#pragma unroll
    for (int ks = 0; ks < 16; ks++) {
        const int ksn = (ks + 1 < 16) ? ks + 1 : ks;
        bf16x8 n0 = *(const bf16x8*)(b2frag + ksn * 512);
        bf16x8 af = *(const bf16x8*)&hsb[c16][ks * 32 + quad * 8];
        acc2 = __builtin_amdgcn_mfma_f32_16x16x32_bf16(af, b20, acc2, 0, 0, 0);
        b20 = n0;
    }
#pragma unroll
    for (int reg = 0; reg < 4; reg++)
        Cs[quad * 4 + reg][w * 16 + c16] = acc2[reg];
    __syncthreads();

    // ---- LN2: 2-stage row reduction over Cs[16][256] ----
    if (t < 256) {
        const int row = t >> 4, seg = t & 15;
        float s = 0.f, s2 = 0.f;
#pragma unroll
        for (int j = 0; j < 16; j++) { float v = Cs[row][seg * 16 + j]; s += v; s2 += v * v; }
        ps1[row][seg] = s; ps2[row][seg] = s2;
    }
    __syncthreads();
    if (t < 16) {
        float s = 0.f, s2 = 0.f;
#pragma unroll
        for (int j = 0; j < 16; j++) { s += ps1[t][j]; s2 += ps2[t][j]; }
        float m = s * (1.0f / DIM);
        float var = s2 * (1.0f / DIM) - m * m;
        mu[t] = m;
        rsd[t] = rsqrtf(var + EPS);
    }
    __syncthreads();

    // write: 1024 threads x float4 = 16 rows x 256 cols
    {
        const int row = t >> 6, c4 = (t & 63) * 4;
        float4 cv = *(const float4*)&Cs[row][c4];
        float4 g4 = *(const float4*)&gamma2[c4];
        const float m = mu[row], rd = rsd[row];
        float4 o;
        o.x = (cv.x - m) * rd * g4.x;
        o.y = (cv.y - m) * rd * g4.y;
        o.z = (cv.z - m) * rd * g4.z;
        o.w = (cv.w - m) * rd * g4.w;
        *(float4*)&out[(size_t)(r0 + row) * DIM + c4] = o;
    }
}

// ---------------------------------------------------------------------------
extern "C" void kernel_launch(void* const* d_in, const int* in_sizes, int n_in,
                              void* d_out, int out_size, void* d_ws, size_t ws_size,
                              hipStream_t stream) {
    const float* x      = (const float*)d_in[0];
    const float* Wq     = (const float*)d_in[1];
    const float* Wk     = (const float*)d_in[2];
    const float* Wv     = (const float*)d_in[3];
    const float* Wo     = (const float*)d_in[4];
    const float* Wf1    = (const float*)d_in[5];
    const float* Wf2    = (const float*)d_in[6];
    const float* gamma1 = (const float*)d_in[7];
    const float* gamma2 = (const float*)d_in[8];
    float* out = (float*)d_out;

    // workspace layout: round-8 + 3 packed qkv weights appended.
    char* base = (char*)d_ws;
    unsigned short* qb   = (unsigned short*)(base);              // 2 MB
    unsigned short* kb   = (unsigned short*)(base +  2097152);   // 2 MB
    unsigned short* vtb  = (unsigned short*)(base +  4194304);   // 2 MB
    float* attout        = (float*)         (base +  6291456);   // 32 MB
    unsigned short* ln1b = (unsigned short*)(base + 39845888);   // 2 MB
    unsigned short* W1P  = (unsigned short*)(base + 41943040);   // 256 KB
    unsigned short* W2P  = (unsigned short*)(base + 42205184);   // 256 KB
    unsigned short* WoP  = (unsigned short*)(base + 44040192);   // 1 MB -> 45088768
    unsigned short* WqP  = (unsigned short*)(base + 45088768);   // 128 KB
    unsigned short* WkP  = (unsigned short*)(base + 45219840);   // 128 KB
    unsigned short* WvP  = (unsigned short*)(base + 45350912);   // 128 KB -> 45481984

    wprep<<<64, 256, 0, stream>>>(Wo, Wf1, Wf2, Wq, Wk, Wv,
                                  WoP, W1P, W2P, WqP, WkP, WvP);
    qkv_mfma<<<NROWS / 16, 1024, 0, stream>>>(x, WqP, WkP, WvP, qb, kb, vtb);
    attn_mfma<<<(SEQ / 64) * HEADS * BATCH, 256, 0, stream>>>(qb, kb, vtb, attout);
    wo_ln_mfma<<<NROWS / 16, 1024, 0, stream>>>(attout, WoP, x, gamma1, ln1b);
    ffn_ln<<<NROWS / 16, 1024, 0, stream>>>(ln1b, W1P, W2P, gamma2, out);
}

// Round 12
// 170.903 us; speedup vs baseline: 1.6427x; 1.1368x over previous
//
#include <hip/hip_runtime.h>
#include <hip/hip_bf16.h>

#define DIM 256
#define HEADS 8
#define DHEAD 32
#define SEQ 2048
#define BATCH 2
#define NROWS (BATCH*SEQ)    // 4096 total rows
#define EPS 1e-5f

typedef __attribute__((ext_vector_type(8))) short bf16x8;   // MFMA A/B frag (4 VGPRs)
typedef __attribute__((ext_vector_type(4))) short bf16x4;   // 4 bf16 (8B)
typedef __attribute__((ext_vector_type(4))) float f32x4;    // MFMA C/D frag

__device__ __forceinline__ unsigned short f2b(float f) {
    __hip_bfloat16 h = __float2bfloat16(f);
    return *reinterpret_cast<unsigned short*>(&h);
}

// ---------------------------------------------------------------------------
// Kernel 1: MFMA qkv projection, packed weights; V written FRAGMENT-PACKED.
//   VP[ ((b*32 + jt)*32 + ctile16*2 + kh)*512 + (quad_v*16 + c16v)*8 + j ]
//     = V[col][key],  col = ctile16*16+c16v,
//       key = jt*64 + kh*32 + quad_v*8 + j.
// ---------------------------------------------------------------------------
__global__ __launch_bounds__(1024) void qkv_mfma(
        const float* __restrict__ x,
        const unsigned short* __restrict__ WqP,
        const unsigned short* __restrict__ WkP,
        const unsigned short* __restrict__ WvP,
        unsigned short* __restrict__ qo,
        unsigned short* __restrict__ ko,
        unsigned short* __restrict__ VP) {
    __shared__ __align__(16) unsigned short xsb[16][264];

    const int t    = threadIdx.x;         // 0..1023
    const int w    = t >> 6;              // wave 0..15 = n-tile
    const int lane = t & 63;
    const int quad = lane >> 4;
    const int c16  = lane & 15;
    const int r0   = blockIdx.x * 16;
    const f32x4 zero = (f32x4){0.f, 0.f, 0.f, 0.f};

    // stage A: 16 rows x 256 cols fp32 -> bf16 LDS (1024 x float4)
    {
        const int row = t >> 6, c4 = (t & 63) * 4;
        float4 v4 = *(const float4*)&x[(size_t)(r0 + row) * 256 + c4];
        bf16x4 b4;
        b4[0] = (short)f2b(v4.x); b4[1] = (short)f2b(v4.y);
        b4[2] = (short)f2b(v4.z); b4[3] = (short)f2b(v4.w);
        *(bf16x4*)&xsb[row][c4] = b4;
    }

    f32x4 aq = zero, ak = zero, av = zero;
    const unsigned short* bq = WqP + (size_t)w * 4096 + (size_t)lane * 8;
    const unsigned short* bk = WkP + (size_t)w * 4096 + (size_t)lane * 8;
    const unsigned short* bv = WvP + (size_t)w * 4096 + (size_t)lane * 8;

    bf16x8 q0 = *(const bf16x8*)(bq);
    bf16x8 k0 = *(const bf16x8*)(bk);
    bf16x8 v0 = *(const bf16x8*)(bv);
    __syncthreads();   // xsb visible

#pragma unroll
    for (int ks = 0; ks < 8; ks++) {
        const int ksn = (ks + 1 < 8) ? ks + 1 : ks;     // last iter: dummy
        bf16x8 qn = *(const bf16x8*)(bq + ksn * 512);
        bf16x8 kn = *(const bf16x8*)(bk + ksn * 512);
        bf16x8 vn = *(const bf16x8*)(bv + ksn * 512);
        bf16x8 af = *(const bf16x8*)&xsb[c16][ks * 32 + quad * 8];
        aq = __builtin_amdgcn_mfma_f32_16x16x32_bf16(af, q0, aq, 0, 0, 0);
        ak = __builtin_amdgcn_mfma_f32_16x16x32_bf16(af, k0, ak, 0, 0, 0);
        av = __builtin_amdgcn_mfma_f32_16x16x32_bf16(af, v0, av, 0, 0, 0);
        q0 = qn; k0 = kn; v0 = vn;
    }

    // epilogue (C/D layout: row=quad*4+reg, col=w*16+c16)
    const float scale = 0.17677669529663687f;  // 1/sqrt(32)
    const int col = w * 16 + c16;
#pragma unroll
    for (int reg = 0; reg < 4; reg++) {
        const int row = r0 + quad * 4 + reg;
        qo[(size_t)row * 256 + col] = f2b(aq[reg] * scale);
        ko[(size_t)row * 256 + col] = f2b(ak[reg]);
    }
    {   // V fragment-packed: 4 consecutive j slots of one (jt,kh,quad_v) frag
        const int bb   = r0 >> 11;
        const int key  = (r0 & 2047) + quad * 4;          // first of 4 keys
        const int jt   = key >> 6;
        const int kh   = (key >> 5) & 1;
        const int qv   = (key >> 3) & 3;
        const int j0   = key & 7;                          // 0 or 4
        const size_t off = ((((size_t)(bb * 32 + jt) * 32) + (w * 2 + kh)) * 64
                            + qv * 16 + c16) * 8 + j0;
        bf16x4 v4;
        v4[0] = (short)f2b(av[0]); v4[1] = (short)f2b(av[1]);
        v4[2] = (short)f2b(av[2]); v4[3] = (short)f2b(av[3]);
        *(bf16x4*)&VP[off] = v4;
    }
}

// ---------------------------------------------------------------------------
// Kernel 2: flash attention, V fragment-direct.
//  - V never touches LDS: per iter each wave loads its 8 PV B-fragments
//    as contiguous 1KB coalesced reads from VP (L2-resident).
//  - LDS holds only Ks (staged, shared by 4 waves) + Ps + linv (~14KB).
//  - attout written as BF16 (halves write traffic; wo_ln reads bf16).
// ---------------------------------------------------------------------------
__global__ __launch_bounds__(256, 2) void attn_mfma(
        const unsigned short* __restrict__ qb,
        const unsigned short* __restrict__ kb,
        const unsigned short* __restrict__ VP,
        unsigned short* __restrict__ attoutb) {
    __shared__ __align__(16) unsigned short Ks[64][40];   // 64 keys x 32 dims
    __shared__ __align__(16) unsigned short Ps[64][68];   // shared P tile
    __shared__ float linv[64];

    const int t    = threadIdx.x;
    const int w    = t >> 6;
    const int lane = t & 63;
    const int quad = lane >> 4;
    const int c16  = lane & 15;

    const int fid  = blockIdx.x;
    const int h    = fid & 7;
    const int b    = (fid >> 3) & 1;
    const int i0b  = (fid >> 4) * 64;        // block q-row base
    const int i0   = i0b + w * 16;           // this wave's q rows (QK phase)

    const size_t qk_head = ((size_t)b * SEQ) * DIM + h * DHEAD;
    const int ncol0 = w * 64;                // this wave's PV column slice

    bf16x8 qf = *(const bf16x8*)&qb[qk_head + (size_t)(i0 + c16) * DIM + quad * 8];

    const int kkey  = t >> 2, kpart = t & 3;                 // K: 1 frag/thread
    const unsigned short* ksrc = kb + qk_head + (size_t)kkey * DIM + kpart * 8;

    f32x4 acc[4][4];
#pragma unroll
    for (int rt = 0; rt < 4; rt++)
#pragma unroll
        for (int ct = 0; ct < 4; ct++) acc[rt][ct] = (f32x4){0.f, 0.f, 0.f, 0.f};
    float lrow[4] = {0.f, 0.f, 0.f, 0.f};
    const f32x4 zero = (f32x4){0.f, 0.f, 0.f, 0.f};

    bf16x8 kreg = *(const bf16x8*)(ksrc);

    for (int jt = 0; jt < SEQ / 64; jt++) {
        __syncthreads();   // (A) all waves done reading Ks/Ps of jt-1
        *(bf16x8*)&Ks[kkey][kpart * 8] = kreg;
        __syncthreads();   // (B) K tile jt visible

        // V fragments for THIS tile: 8 coalesced 1KB loads, consumed after (C)
        const unsigned short* vsrc = VP +
            (((size_t)(b * 32 + jt) * 32) + w * 8) * 512 + (size_t)lane * 8;
        bf16x8 vreg[8];
#pragma unroll
        for (int ct = 0; ct < 4; ct++) {
            vreg[0 * 4 + ct] = *(const bf16x8*)(vsrc + (ct * 2 + 0) * 512);
            vreg[1 * 4 + ct] = *(const bf16x8*)(vsrc + (ct * 2 + 1) * 512);
        }

        // K prefetch for jt+1 (retires under compute)
        if (jt + 1 < SEQ / 64) {
            kreg = *(const bf16x8*)(ksrc + (size_t)((jt + 1) * 64) * DIM);
        }

        // ---- QK^T (M-split): this wave's 16 rows vs 64 keys, K from LDS
        f32x4 s[4];
#pragma unroll
        for (int kt = 0; kt < 4; kt++) {
            bf16x8 kf = *(const bf16x8*)&Ks[kt * 16 + c16][quad * 8];
            s[kt] = __builtin_amdgcn_mfma_f32_16x16x32_bf16(qf, kf, zero, 0, 0, 0);
        }

        // ---- softmax (no max subtraction), stash P into SHARED tile
#pragma unroll
        for (int kt = 0; kt < 4; kt++) {
#pragma unroll
            for (int reg = 0; reg < 4; reg++) {
                float p = __expf(s[kt][reg]);
                lrow[reg] += p;
                Ps[w * 16 + quad * 4 + reg][kt * 16 + c16] = f2b(p);
            }
        }
        __syncthreads();   // (C) P visible to all waves

        // ---- PV (N-split): all 64 rows x this wave's 64 cols, V from regs
#pragma unroll
        for (int kh = 0; kh < 2; kh++) {
#pragma unroll
            for (int rt = 0; rt < 4; rt++) {
                bf16x8 af = *(const bf16x8*)&Ps[rt * 16 + c16][kh * 32 + quad * 8];
#pragma unroll
                for (int ct = 0; ct < 4; ct++)
                    acc[rt][ct] = __builtin_amdgcn_mfma_f32_16x16x32_bf16(
                        af, vreg[kh * 4 + ct], acc[rt][ct], 0, 0, 0);
            }
        }
    }

    // ---- l broadcast: owner wave writes 1/l for its 16 rows
#pragma unroll
    for (int reg = 0; reg < 4; reg++) {
        float l = lrow[reg];
#pragma unroll
        for (int m = 1; m <= 8; m <<= 1) l += __shfl_xor(l, m, 64);
        if (c16 == 0) linv[w * 16 + quad * 4 + reg] = 1.f / l;
    }
    __syncthreads();

    // ---- write out (bf16): rows i0b+rt*16+quad*4+reg, cols h*256+ncol0+ct*16+c16
#pragma unroll
    for (int rt = 0; rt < 4; rt++) {
#pragma unroll
        for (int reg = 0; reg < 4; reg++) {
            const int row = i0b + rt * 16 + quad * 4 + reg;
            const float inv = linv[rt * 16 + quad * 4 + reg];
#pragma unroll
            for (int ct = 0; ct < 4; ct++) {
                attoutb[((size_t)b * SEQ + row) * (size_t)(HEADS * DIM) +
                        h * DIM + ncol0 + ct * 16 + c16] = f2b(acc[rt][ct][reg] * inv);
            }
        }
    }
}

// ---------------------------------------------------------------------------
// Kernel 3: MFMA-fragment-packed bf16 weights.
// ---------------------------------------------------------------------------
__global__ void wprep(const float* __restrict__ Wo,
                      const float* __restrict__ Wf1,
                      const float* __restrict__ Wf2,
                      const float* __restrict__ Wq,
                      const float* __restrict__ Wk,
                      const float* __restrict__ Wv,
                      unsigned short* __restrict__ WoP,
                      unsigned short* __restrict__ W1P,
                      unsigned short* __restrict__ W2P,
                      unsigned short* __restrict__ WqP,
                      unsigned short* __restrict__ WkP,
                      unsigned short* __restrict__ WvP) {
    const int tid = blockIdx.x * 256 + threadIdx.x;
    const int stride = gridDim.x * 256;
    const int N1 = 524288;            // WoP
    const int N2 = N1 + 131072;       // W1P
    const int N3 = N2 + 131072;       // W2P
    const int N4 = N3 + 65536;        // WqP
    const int N5 = N4 + 65536;        // WkP
    const int N6 = N5 + 65536;        // WvP
    for (int i = tid; i < N6; i += stride) {
        if (i < N1) {
            int j = i & 7, l = (i >> 3) & 63, KS = (i >> 9) & 63, NT = i >> 15;
            int n = NT * 16 + (l & 15);
            int k = KS * 32 + ((l >> 4) << 3) + j;
            WoP[i] = f2b(Wo[k * 256 + n]);
        } else if (i < N2) {
            int i2 = i - N1;
            int j = i2 & 7, l = (i2 >> 3) & 63, KS = (i2 >> 9) & 7, NT = i2 >> 12;
            int n = NT * 16 + (l & 15);
            int k = KS * 32 + ((l >> 4) << 3) + j;
            W1P[i2] = f2b(Wf1[k * 512 + n]);
        } else if (i < N3) {
            int i2 = i - N2;
            int j = i2 & 7, l = (i2 >> 3) & 63, KS = (i2 >> 9) & 15, NT = i2 >> 13;
            int n = NT * 16 + (l & 15);
            int k = KS * 32 + ((l >> 4) << 3) + j;
            W2P[i2] = f2b(Wf2[k * 256 + n]);
        } else {
            int i2 = (i - N3) & 65535;
            int j = i2 & 7, l = (i2 >> 3) & 63, KS = (i2 >> 9) & 7, NT = i2 >> 12;
            int n = NT * 16 + (l & 15);
            int k = KS * 32 + ((l >> 4) << 3) + j;
            float v = (i < N4) ? Wq[k * 256 + n] : (i < N5) ? Wk[k * 256 + n]
                                                            : Wv[k * 256 + n];
            unsigned short* dst = (i < N4) ? WqP : (i < N5) ? WkP : WvP;
            dst[i2] = f2b(v);
        }
    }
}

// ---------------------------------------------------------------------------
// Kernel 4: MFMA wo + residual + LN1 -> bf16 ln1 (attout read as bf16).
// ---------------------------------------------------------------------------
__global__ __launch_bounds__(1024) void wo_ln_mfma(
        const unsigned short* __restrict__ attoutb,  // [4096][2048] bf16
        const unsigned short* __restrict__ WoP,      // fragment-packed bf16
        const float* __restrict__ x,
        const float* __restrict__ gamma1,
        unsigned short* __restrict__ ln1b) {         // [4096][256] bf16
    __shared__ __align__(16) float Cp[4][16][264];   // per-kslice partial C
    __shared__ float ps1[16][16], ps2[16][16];
    __shared__ float mu[16], rsd[16];

    const int t      = threadIdx.x;          // 0..1023
    const int wave   = t >> 6;               // 0..15
    const int kslice = wave >> 2;            // 0..3  -> k0 = kslice*512
    const int wn     = wave & 3;             // col group n0 = wn*64
    const int lane   = t & 63;
    const int quad   = lane >> 4;
    const int c16    = lane & 15;
    const int r0     = blockIdx.x * 16;

    const size_t k0 = (size_t)kslice * 512;
    const unsigned short* arow = attoutb + (size_t)(r0 + c16) * 2048 + k0 + quad * 8;
    const unsigned short* bfrag = WoP + (size_t)wn * 131072 + (size_t)kslice * 8192
                                      + (size_t)lane * 8;

    f32x4 acc[4];
#pragma unroll
    for (int nt = 0; nt < 4; nt++) acc[nt] = (f32x4){0.f, 0.f, 0.f, 0.f};

    bf16x8 aa = *(const bf16x8*)(arow);
    bf16x8 bb[4];
#pragma unroll
    for (int nt = 0; nt < 4; nt++) bb[nt] = *(const bf16x8*)(bfrag + nt * 32768);

    for (int kc = 0; kc < 512; kc += 32) {
        const int kn  = (kc + 32 < 512) ? kc + 32 : kc;     // last iter: dummy
        const int ksn = kn >> 5;
        bf16x8 na = *(const bf16x8*)(arow + kn);
        bf16x8 nb[4];
#pragma unroll
        for (int nt = 0; nt < 4; nt++)
            nb[nt] = *(const bf16x8*)(bfrag + nt * 32768 + ksn * 512);

#pragma unroll
        for (int nt = 0; nt < 4; nt++)
            acc[nt] = __builtin_amdgcn_mfma_f32_16x16x32_bf16(aa, bb[nt], acc[nt], 0, 0, 0);

        aa = na;
#pragma unroll
        for (int nt = 0; nt < 4; nt++) bb[nt] = nb[nt];
    }

#pragma unroll
    for (int reg = 0; reg < 4; reg++) {
        const int row = quad * 4 + reg;
#pragma unroll
        for (int nt = 0; nt < 4; nt++)
            Cp[kslice][row][wn * 64 + nt * 16 + c16] = acc[nt][reg];
    }
    __syncthreads();

#pragma unroll
    for (int p = 0; p < 4; p++) {
        const int idx = t + p * 1024;
        const int row = idx >> 8, col = idx & 255;
        float v = Cp[0][row][col] + Cp[1][row][col] + Cp[2][row][col] + Cp[3][row][col]
                + x[(size_t)(r0 + row) * 256 + col];
        Cp[0][row][col] = v;
    }
    __syncthreads();

    if (t < 256) {
        const int row = t >> 4, seg = t & 15;
        float s = 0.f, s2 = 0.f;
#pragma unroll
        for (int j = 0; j < 16; j++) { float v = Cp[0][row][seg * 16 + j]; s += v; s2 += v * v; }
        ps1[row][seg] = s; ps2[row][seg] = s2;
    }
    __syncthreads();
    if (t < 16) {
        float s = 0.f, s2 = 0.f;
#pragma unroll
        for (int j = 0; j < 16; j++) { s += ps1[t][j]; s2 += ps2[t][j]; }
        float m = s * (1.0f / 256.0f);
        float var = s2 * (1.0f / 256.0f) - m * m;
        mu[t] = m; rsd[t] = rsqrtf(var + EPS);
    }
    __syncthreads();

    {
        const int row = t >> 6;
        const int c4  = (t & 63) * 4;
        float4 cv = *(const float4*)&Cp[0][row][c4];
        float4 g4 = *(const float4*)&gamma1[c4];
        const float m = mu[row], rd = rsd[row];
        bf16x4 o4;
        o4[0] = (short)f2b((cv.x - m) * rd * g4.x);
        o4[1] = (short)f2b((cv.y - m) * rd * g4.y);
        o4[2] = (short)f2b((cv.z - m) * rd * g4.z);
        o4[3] = (short)f2b((cv.w - m) * rd * g4.w);
        *(bf16x4*)&ln1b[(size_t)(r0 + row) * 256 + c4] = o4;
    }
}

// ---------------------------------------------------------------------------
// Kernel 5: MFMA bf16 FFN + LN2, packed weights.
// ---------------------------------------------------------------------------
__global__ __launch_bounds__(1024) void ffn_ln(
        const unsigned short* __restrict__ ln1b,  // [4096][256] bf16
        const unsigned short* __restrict__ W1P,   // fragment-packed bf16
        const unsigned short* __restrict__ W2P,   // fragment-packed bf16
        const float* __restrict__ gamma2,
        float* __restrict__ out) {
    __shared__ __align__(16) unsigned short xsb[16][264];  // A1 (bf16)
    __shared__ __align__(16) unsigned short hsb[16][520];  // relu(h) (bf16)
    __shared__ __align__(16) float Cs[16][264];            // C (fp32)
    __shared__ float ps1[16][16], ps2[16][16];
    __shared__ float mu[16], rsd[16];

    const int t    = threadIdx.x;         // 0..1023
    const int w    = t >> 6;              // wave 0..15
    const int lane = t & 63;
    const int quad = lane >> 4;
    const int c16  = lane & 15;
    const int r0   = blockIdx.x * 16;
    const f32x4 zero = (f32x4){0.f, 0.f, 0.f, 0.f};

    // stage A: 16 rows x 256 cols bf16 (4 shorts/thread)
    {
        const int row = t >> 6, c4 = (t & 63) * 4;
        *(bf16x4*)&xsb[row][c4] = *(const bf16x4*)&ln1b[(size_t)(r0 + row) * 256 + c4];
    }

    // ---- GEMM1: h = relu(A @ Wf1), wave tile 16x32, packed B ----
    f32x4 acc1[2];
    acc1[0] = zero; acc1[1] = zero;
    const unsigned short* b1frag = W1P + (size_t)(w * 2) * 4096 + (size_t)lane * 8;
    bf16x8 b10 = *(const bf16x8*)(b1frag);
    bf16x8 b11 = *(const bf16x8*)(b1frag + 4096);
    __syncthreads();   // xsb visible

#pragma unroll
    for (int ks = 0; ks < 8; ks++) {
        const int ksn = (ks + 1 < 8) ? ks + 1 : ks;
        bf16x8 n0 = *(const bf16x8*)(b1frag + ksn * 512);
        bf16x8 n1 = *(const bf16x8*)(b1frag + 4096 + ksn * 512);
        bf16x8 af = *(const bf16x8*)&xsb[c16][ks * 32 + quad * 8];
        acc1[0] = __builtin_amdgcn_mfma_f32_16x16x32_bf16(af, b10, acc1[0], 0, 0, 0);
        acc1[1] = __builtin_amdgcn_mfma_f32_16x16x32_bf16(af, b11, acc1[1], 0, 0, 0);
        b10 = n0; b11 = n1;
    }

    // relu + bf16 -> hsb (C/D layout: row=quad*4+reg, col=w*32+nt*16+c16)
#pragma unroll
    for (int nt = 0; nt < 2; nt++)
#pragma unroll
        for (int reg = 0; reg < 4; reg++)
            hsb[quad * 4 + reg][w * 32 + nt * 16 + c16] =
                f2b(fmaxf(acc1[nt][reg], 0.f));
    __syncthreads();

    // ---- GEMM2: C = h @ Wf2, wave tile 16x16, packed B ----
    f32x4 acc2 = zero;
    const unsigned short* b2frag = W2P + (size_t)w * 8192 + (size_t)lane * 8;
    bf16x8 b20 = *(const bf16x8*)(b2frag);
#pragma unroll
    for (int ks = 0; ks < 16; ks++) {
        const int ksn = (ks + 1 < 16) ? ks + 1 : ks;
        bf16x8 n0 = *(const bf16x8*)(b2frag + ksn * 512);
        bf16x8 af = *(const bf16x8*)&hsb[c16][ks * 32 + quad * 8];
        acc2 = __builtin_amdgcn_mfma_f32_16x16x32_bf16(af, b20, acc2, 0, 0, 0);
        b20 = n0;
    }
#pragma unroll
    for (int reg = 0; reg < 4; reg++)
        Cs[quad * 4 + reg][w * 16 + c16] = acc2[reg];
    __syncthreads();

    // ---- LN2: 2-stage row reduction over Cs[16][256] ----
    if (t < 256) {
        const int row = t >> 4, seg = t & 15;
        float s = 0.f, s2 = 0.f;
#pragma unroll
        for (int j = 0; j < 16; j++) { float v = Cs[row][seg * 16 + j]; s += v; s2 += v * v; }
        ps1[row][seg] = s; ps2[row][seg] = s2;
    }
    __syncthreads();
    if (t < 16) {
        float s = 0.f, s2 = 0.f;
#pragma unroll
        for (int j = 0; j < 16; j++) { s += ps1[t][j]; s2 += ps2[t][j]; }
        float m = s * (1.0f / DIM);
        float var = s2 * (1.0f / DIM) - m * m;
        mu[t] = m;
        rsd[t] = rsqrtf(var + EPS);
    }
    __syncthreads();

    // write: 1024 threads x float4 = 16 rows x 256 cols
    {
        const int row = t >> 6, c4 = (t & 63) * 4;
        float4 cv = *(const float4*)&Cs[row][c4];
        float4 g4 = *(const float4*)&gamma2[c4];
        const float m = mu[row], rd = rsd[row];
        float4 o;
        o.x = (cv.x - m) * rd * g4.x;
        o.y = (cv.y - m) * rd * g4.y;
        o.z = (cv.z - m) * rd * g4.z;
        o.w = (cv.w - m) * rd * g4.w;
        *(float4*)&out[(size_t)(r0 + row) * DIM + c4] = o;
    }
}

// ---------------------------------------------------------------------------
extern "C" void kernel_launch(void* const* d_in, const int* in_sizes, int n_in,
                              void* d_out, int out_size, void* d_ws, size_t ws_size,
                              hipStream_t stream) {
    const float* x      = (const float*)d_in[0];
    const float* Wq     = (const float*)d_in[1];
    const float* Wk     = (const float*)d_in[2];
    const float* Wv     = (const float*)d_in[3];
    const float* Wo     = (const float*)d_in[4];
    const float* Wf1    = (const float*)d_in[5];
    const float* Wf2    = (const float*)d_in[6];
    const float* gamma1 = (const float*)d_in[7];
    const float* gamma2 = (const float*)d_in[8];
    float* out = (float*)d_out;

    // workspace layout: vtb slot now VP; attout slot now bf16 (16MB used).
    char* base = (char*)d_ws;
    unsigned short* qb      = (unsigned short*)(base);              // 2 MB
    unsigned short* kb      = (unsigned short*)(base +  2097152);   // 2 MB
    unsigned short* VP      = (unsigned short*)(base +  4194304);   // 2 MB
    unsigned short* attoutb = (unsigned short*)(base +  6291456);   // 16 MB (of 32MB slot)
    unsigned short* ln1b    = (unsigned short*)(base + 39845888);   // 2 MB
    unsigned short* W1P     = (unsigned short*)(base + 41943040);   // 256 KB
    unsigned short* W2P     = (unsigned short*)(base + 42205184);   // 256 KB
    unsigned short* WoP     = (unsigned short*)(base + 44040192);   // 1 MB -> 45088768
    unsigned short* WqP     = (unsigned short*)(base + 45088768);   // 128 KB
    unsigned short* WkP     = (unsigned short*)(base + 45219840);   // 128 KB
    unsigned short* WvP     = (unsigned short*)(base + 45350912);   // 128 KB -> 45481984

    wprep<<<64, 256, 0, stream>>>(Wo, Wf1, Wf2, Wq, Wk, Wv,
                                  WoP, W1P, W2P, WqP, WkP, WvP);
    qkv_mfma<<<NROWS / 16, 1024, 0, stream>>>(x, WqP, WkP, WvP, qb, kb, VP);
    attn_mfma<<<(SEQ / 64) * HEADS * BATCH, 256, 0, stream>>>(qb, kb, VP, attoutb);
    wo_ln_mfma<<<NROWS / 16, 1024, 0, stream>>>(attoutb, WoP, x, gamma1, ln1b);
    ffn_ln<<<NROWS / 16, 1024, 0, stream>>>(ln1b, W1P, W2P, gamma2, out);
}

// Round 13
// 152.314 us; speedup vs baseline: 1.8431x; 1.1220x over previous
//
#include <hip/hip_runtime.h>
#include <hip/hip_bf16.h>

#define DIM 256
#define HEADS 8
#define DHEAD 32
#define SEQ 2048
#define BATCH 2
#define NROWS (BATCH*SEQ)    // 4096 total rows
#define EPS 1e-5f

typedef __attribute__((ext_vector_type(8))) short bf16x8;   // MFMA A/B frag (4 VGPRs)
typedef __attribute__((ext_vector_type(4))) short bf16x4;   // 4 bf16 (8B)
typedef __attribute__((ext_vector_type(4))) float f32x4;    // MFMA C/D frag

__device__ __forceinline__ unsigned short f2b(float f) {
    __hip_bfloat16 h = __float2bfloat16(f);
    return *reinterpret_cast<unsigned short*>(&h);
}

// ---------------------------------------------------------------------------
// Kernel 1 (VERBATIM, passed): MFMA qkv projection; V written fragment-packed.
// ---------------------------------------------------------------------------
__global__ __launch_bounds__(1024) void qkv_mfma(
        const float* __restrict__ x,
        const unsigned short* __restrict__ WqP,
        const unsigned short* __restrict__ WkP,
        const unsigned short* __restrict__ WvP,
        unsigned short* __restrict__ qo,
        unsigned short* __restrict__ ko,
        unsigned short* __restrict__ VP) {
    __shared__ __align__(16) unsigned short xsb[16][264];

    const int t    = threadIdx.x;         // 0..1023
    const int w    = t >> 6;              // wave 0..15 = n-tile
    const int lane = t & 63;
    const int quad = lane >> 4;
    const int c16  = lane & 15;
    const int r0   = blockIdx.x * 16;
    const f32x4 zero = (f32x4){0.f, 0.f, 0.f, 0.f};

    // stage A: 16 rows x 256 cols fp32 -> bf16 LDS (1024 x float4)
    {
        const int row = t >> 6, c4 = (t & 63) * 4;
        float4 v4 = *(const float4*)&x[(size_t)(r0 + row) * 256 + c4];
        bf16x4 b4;
        b4[0] = (short)f2b(v4.x); b4[1] = (short)f2b(v4.y);
        b4[2] = (short)f2b(v4.z); b4[3] = (short)f2b(v4.w);
        *(bf16x4*)&xsb[row][c4] = b4;
    }

    f32x4 aq = zero, ak = zero, av = zero;
    const unsigned short* bq = WqP + (size_t)w * 4096 + (size_t)lane * 8;
    const unsigned short* bk = WkP + (size_t)w * 4096 + (size_t)lane * 8;
    const unsigned short* bv = WvP + (size_t)w * 4096 + (size_t)lane * 8;

    bf16x8 q0 = *(const bf16x8*)(bq);
    bf16x8 k0 = *(const bf16x8*)(bk);
    bf16x8 v0 = *(const bf16x8*)(bv);
    __syncthreads();   // xsb visible

#pragma unroll
    for (int ks = 0; ks < 8; ks++) {
        const int ksn = (ks + 1 < 8) ? ks + 1 : ks;     // last iter: dummy
        bf16x8 qn = *(const bf16x8*)(bq + ksn * 512);
        bf16x8 kn = *(const bf16x8*)(bk + ksn * 512);
        bf16x8 vn = *(const bf16x8*)(bv + ksn * 512);
        bf16x8 af = *(const bf16x8*)&xsb[c16][ks * 32 + quad * 8];
        aq = __builtin_amdgcn_mfma_f32_16x16x32_bf16(af, q0, aq, 0, 0, 0);
        ak = __builtin_amdgcn_mfma_f32_16x16x32_bf16(af, k0, ak, 0, 0, 0);
        av = __builtin_amdgcn_mfma_f32_16x16x32_bf16(af, v0, av, 0, 0, 0);
        q0 = qn; k0 = kn; v0 = vn;
    }

    // epilogue (C/D layout: row=quad*4+reg, col=w*16+c16)
    const float scale = 0.17677669529663687f;  // 1/sqrt(32)
    const int col = w * 16 + c16;
#pragma unroll
    for (int reg = 0; reg < 4; reg++) {
        const int row = r0 + quad * 4 + reg;
        qo[(size_t)row * 256 + col] = f2b(aq[reg] * scale);
        ko[(size_t)row * 256 + col] = f2b(ak[reg]);
    }
    {   // V fragment-packed
        const int bb   = r0 >> 11;
        const int key  = (r0 & 2047) + quad * 4;          // first of 4 keys
        const int jt   = key >> 6;
        const int kh   = (key >> 5) & 1;
        const int qv   = (key >> 3) & 3;
        const int j0   = key & 7;                          // 0 or 4
        const size_t off = ((((size_t)(bb * 32 + jt) * 32) + (w * 2 + kh)) * 64
                            + qv * 16 + c16) * 8 + j0;
        bf16x4 v4;
        v4[0] = (short)f2b(av[0]); v4[1] = (short)f2b(av[1]);
        v4[2] = (short)f2b(av[2]); v4[3] = (short)f2b(av[3]);
        *(bf16x4*)&VP[off] = v4;
    }
}

// ---------------------------------------------------------------------------
// Kernel 2 (VERBATIM, passed): flash attention, V fragment-direct (51.8 us).
// ---------------------------------------------------------------------------
__global__ __launch_bounds__(256, 2) void attn_mfma(
        const unsigned short* __restrict__ qb,
        const unsigned short* __restrict__ kb,
        const unsigned short* __restrict__ VP,
        unsigned short* __restrict__ attoutb) {
    __shared__ __align__(16) unsigned short Ks[64][40];   // 64 keys x 32 dims
    __shared__ __align__(16) unsigned short Ps[64][68];   // shared P tile
    __shared__ float linv[64];

    const int t    = threadIdx.x;
    const int w    = t >> 6;
    const int lane = t & 63;
    const int quad = lane >> 4;
    const int c16  = lane & 15;

    const int fid  = blockIdx.x;
    const int h    = fid & 7;
    const int b    = (fid >> 3) & 1;
    const int i0b  = (fid >> 4) * 64;        // block q-row base
    const int i0   = i0b + w * 16;           // this wave's q rows (QK phase)

    const size_t qk_head = ((size_t)b * SEQ) * DIM + h * DHEAD;
    const int ncol0 = w * 64;                // this wave's PV column slice

    bf16x8 qf = *(const bf16x8*)&qb[qk_head + (size_t)(i0 + c16) * DIM + quad * 8];

    const int kkey  = t >> 2, kpart = t & 3;                 // K: 1 frag/thread
    const unsigned short* ksrc = kb + qk_head + (size_t)kkey * DIM + kpart * 8;

    f32x4 acc[4][4];
#pragma unroll
    for (int rt = 0; rt < 4; rt++)
#pragma unroll
        for (int ct = 0; ct < 4; ct++) acc[rt][ct] = (f32x4){0.f, 0.f, 0.f, 0.f};
    float lrow[4] = {0.f, 0.f, 0.f, 0.f};
    const f32x4 zero = (f32x4){0.f, 0.f, 0.f, 0.f};

    bf16x8 kreg = *(const bf16x8*)(ksrc);

    for (int jt = 0; jt < SEQ / 64; jt++) {
        __syncthreads();   // (A) all waves done reading Ks/Ps of jt-1
        *(bf16x8*)&Ks[kkey][kpart * 8] = kreg;
        __syncthreads();   // (B) K tile jt visible

        const unsigned short* vsrc = VP +
            (((size_t)(b * 32 + jt) * 32) + w * 8) * 512 + (size_t)lane * 8;
        bf16x8 vreg[8];
#pragma unroll
        for (int ct = 0; ct < 4; ct++) {
            vreg[0 * 4 + ct] = *(const bf16x8*)(vsrc + (ct * 2 + 0) * 512);
            vreg[1 * 4 + ct] = *(const bf16x8*)(vsrc + (ct * 2 + 1) * 512);
        }

        if (jt + 1 < SEQ / 64) {
            kreg = *(const bf16x8*)(ksrc + (size_t)((jt + 1) * 64) * DIM);
        }

        f32x4 s[4];
#pragma unroll
        for (int kt = 0; kt < 4; kt++) {
            bf16x8 kf = *(const bf16x8*)&Ks[kt * 16 + c16][quad * 8];
            s[kt] = __builtin_amdgcn_mfma_f32_16x16x32_bf16(qf, kf, zero, 0, 0, 0);
        }

#pragma unroll
        for (int kt = 0; kt < 4; kt++) {
#pragma unroll
            for (int reg = 0; reg < 4; reg++) {
                float p = __expf(s[kt][reg]);
                lrow[reg] += p;
                Ps[w * 16 + quad * 4 + reg][kt * 16 + c16] = f2b(p);
            }
        }
        __syncthreads();   // (C) P visible to all waves

#pragma unroll
        for (int kh = 0; kh < 2; kh++) {
#pragma unroll
            for (int rt = 0; rt < 4; rt++) {
                bf16x8 af = *(const bf16x8*)&Ps[rt * 16 + c16][kh * 32 + quad * 8];
#pragma unroll
                for (int ct = 0; ct < 4; ct++)
                    acc[rt][ct] = __builtin_amdgcn_mfma_f32_16x16x32_bf16(
                        af, vreg[kh * 4 + ct], acc[rt][ct], 0, 0, 0);
            }
        }
    }

#pragma unroll
    for (int reg = 0; reg < 4; reg++) {
        float l = lrow[reg];
#pragma unroll
        for (int m = 1; m <= 8; m <<= 1) l += __shfl_xor(l, m, 64);
        if (c16 == 0) linv[w * 16 + quad * 4 + reg] = 1.f / l;
    }
    __syncthreads();

#pragma unroll
    for (int rt = 0; rt < 4; rt++) {
#pragma unroll
        for (int reg = 0; reg < 4; reg++) {
            const int row = i0b + rt * 16 + quad * 4 + reg;
            const float inv = linv[rt * 16 + quad * 4 + reg];
#pragma unroll
            for (int ct = 0; ct < 4; ct++) {
                attoutb[((size_t)b * SEQ + row) * (size_t)(HEADS * DIM) +
                        h * DIM + ncol0 + ct * 16 + c16] = f2b(acc[rt][ct][reg] * inv);
            }
        }
    }
}

// ---------------------------------------------------------------------------
// Kernel 3 (REWRITTEN this round): fragment-packed weights, coalesced reads.
//  One FRAGMENT ROW (8 shorts) per loop step: 8 reads that are fully
//  line-coalesced across the wave (per j, 64 lanes cover 4 complete 64B
//  lines) + one 16B store.  Replaces the 1-short/1-scalar-read/1-2B-write
//  version (983K scalar ops, 16-way read scatter).
//  Mapping identical to round 8: n = NT*16+(l&15), k = KS*32+(l>>4)*8+j.
// ---------------------------------------------------------------------------
__global__ void wprep(const float* __restrict__ Wo,
                      const float* __restrict__ Wf1,
                      const float* __restrict__ Wf2,
                      const float* __restrict__ Wq,
                      const float* __restrict__ Wk,
                      const float* __restrict__ Wv,
                      unsigned short* __restrict__ WoP,
                      unsigned short* __restrict__ W1P,
                      unsigned short* __restrict__ W2P,
                      unsigned short* __restrict__ WqP,
                      unsigned short* __restrict__ WkP,
                      unsigned short* __restrict__ WvP) {
    const int tid = blockIdx.x * 256 + threadIdx.x;
    const int stride = gridDim.x * 256;
    const int R1 = 65536;             // WoP rows  (16 NT x 64 KS x 64 l)
    const int R2 = R1 + 16384;        // W1P rows  (32 NT x  8 KS x 64 l)
    const int R3 = R2 + 16384;        // W2P rows  (16 NT x 16 KS x 64 l)
    const int R4 = R3 + 8192;         // WqP rows  (16 NT x  8 KS x 64 l)
    const int R5 = R4 + 8192;         // WkP rows
    const int R6 = R5 + 8192;         // WvP rows
    for (int r = tid; r < R6; r += stride) {
        const float* src;
        unsigned short* dst;
        int l, kbase, n, K;
        int ro;
        if (r < R1) {
            ro = r; l = ro & 63;
            int KS = (ro >> 6) & 63, NT = ro >> 12;
            n = NT * 16 + (l & 15); kbase = KS * 32 + ((l >> 4) << 3);
            src = Wo; dst = WoP; K = 256;
        } else if (r < R2) {
            ro = r - R1; l = ro & 63;
            int KS = (ro >> 6) & 7, NT = ro >> 9;
            n = NT * 16 + (l & 15); kbase = KS * 32 + ((l >> 4) << 3);
            src = Wf1; dst = W1P; K = 512;
        } else if (r < R3) {
            ro = r - R2; l = ro & 63;
            int KS = (ro >> 6) & 15, NT = ro >> 10;
            n = NT * 16 + (l & 15); kbase = KS * 32 + ((l >> 4) << 3);
            src = Wf2; dst = W2P; K = 256;
        } else {
            ro = (r - R3) & 8191; l = ro & 63;
            int KS = (ro >> 6) & 7, NT = ro >> 9;
            n = NT * 16 + (l & 15); kbase = KS * 32 + ((l >> 4) << 3);
            src = (r < R4) ? Wq : (r < R5) ? Wk : Wv;
            dst = (r < R4) ? WqP : (r < R5) ? WkP : WvP;
            K = 256;
        }
        bf16x8 o;
#pragma unroll
        for (int j = 0; j < 8; j++)
            o[j] = (short)f2b(src[(size_t)(kbase + j) * K + n]);
        *(bf16x8*)&dst[(size_t)ro * 8] = o;
    }
}

// ---------------------------------------------------------------------------
// Kernel 4 (FUSED this round): wo GEMM + residual + LN1 + FFN + LN2.
//  LN1 is row-local and ffn consumed exactly these 16 rows -> the ln1b
//  global round-trip (2MB write + 2MB read) and one kernel launch are
//  pure overhead.  LN1 output goes bf16 -> LDS xsb directly (identical
//  rounding as before -> bit-identical results).  LDS total ~109KB.
// ---------------------------------------------------------------------------
__global__ __launch_bounds__(1024) void wo_ffn_ln(
        const unsigned short* __restrict__ attoutb,  // [4096][2048] bf16
        const unsigned short* __restrict__ WoP,      // fragment-packed bf16
        const float* __restrict__ x,
        const float* __restrict__ gamma1,
        const unsigned short* __restrict__ W1P,      // fragment-packed bf16
        const unsigned short* __restrict__ W2P,      // fragment-packed bf16
        const float* __restrict__ gamma2,
        float* __restrict__ out) {
    __shared__ __align__(16) float Cp[4][16][264];         // wo partial C (66KB)
    __shared__ __align__(16) unsigned short xsb[16][264];  // ln1 (bf16)
    __shared__ __align__(16) unsigned short hsb[16][520];  // relu(h) (bf16)
    __shared__ __align__(16) float Cs[16][264];            // ffn C (fp32)
    __shared__ float ps1[16][16], ps2[16][16];
    __shared__ float mu[16], rsd[16];

    const int t      = threadIdx.x;          // 0..1023
    const int wave   = t >> 6;               // 0..15
    const int kslice = wave >> 2;            // 0..3  (wo phase)
    const int wn     = wave & 3;             // col group (wo phase)
    const int lane   = t & 63;
    const int quad   = lane >> 4;
    const int c16    = lane & 15;
    const int r0     = blockIdx.x * 16;
    const f32x4 zero = (f32x4){0.f, 0.f, 0.f, 0.f};

    // ======== Phase 1: wo GEMM (K split x4), residual, LN1 -> xsb ========
    {
        const size_t k0 = (size_t)kslice * 512;
        const unsigned short* arow = attoutb + (size_t)(r0 + c16) * 2048 + k0 + quad * 8;
        const unsigned short* bfrag = WoP + (size_t)wn * 131072 + (size_t)kslice * 8192
                                          + (size_t)lane * 8;

        f32x4 acc[4];
#pragma unroll
        for (int nt = 0; nt < 4; nt++) acc[nt] = zero;

        bf16x8 aa = *(const bf16x8*)(arow);
        bf16x8 bb[4];
#pragma unroll
        for (int nt = 0; nt < 4; nt++) bb[nt] = *(const bf16x8*)(bfrag + nt * 32768);

        for (int kc = 0; kc < 512; kc += 32) {
            const int kn  = (kc + 32 < 512) ? kc + 32 : kc;     // last: dummy
            const int ksn = kn >> 5;
            bf16x8 na = *(const bf16x8*)(arow + kn);
            bf16x8 nb[4];
#pragma unroll
            for (int nt = 0; nt < 4; nt++)
                nb[nt] = *(const bf16x8*)(bfrag + nt * 32768 + ksn * 512);

#pragma unroll
            for (int nt = 0; nt < 4; nt++)
                acc[nt] = __builtin_amdgcn_mfma_f32_16x16x32_bf16(aa, bb[nt], acc[nt], 0, 0, 0);

            aa = na;
#pragma unroll
            for (int nt = 0; nt < 4; nt++) bb[nt] = nb[nt];
        }

#pragma unroll
        for (int reg = 0; reg < 4; reg++) {
            const int row = quad * 4 + reg;
#pragma unroll
            for (int nt = 0; nt < 4; nt++)
                Cp[kslice][row][wn * 64 + nt * 16 + c16] = acc[nt][reg];
        }
    }
    __syncthreads();

    // reduce 4 k-slices + residual -> Cp[0]
#pragma unroll
    for (int p = 0; p < 4; p++) {
        const int idx = t + p * 1024;
        const int row = idx >> 8, col = idx & 255;
        float v = Cp[0][row][col] + Cp[1][row][col] + Cp[2][row][col] + Cp[3][row][col]
                + x[(size_t)(r0 + row) * 256 + col];
        Cp[0][row][col] = v;
    }
    __syncthreads();

    // LN1 stats
    if (t < 256) {
        const int row = t >> 4, seg = t & 15;
        float s = 0.f, s2 = 0.f;
#pragma unroll
        for (int j = 0; j < 16; j++) { float v = Cp[0][row][seg * 16 + j]; s += v; s2 += v * v; }
        ps1[row][seg] = s; ps2[row][seg] = s2;
    }
    __syncthreads();
    if (t < 16) {
        float s = 0.f, s2 = 0.f;
#pragma unroll
        for (int j = 0; j < 16; j++) { s += ps1[t][j]; s2 += ps2[t][j]; }
        float m = s * (1.0f / 256.0f);
        float var = s2 * (1.0f / 256.0f) - m * m;
        mu[t] = m; rsd[t] = rsqrtf(var + EPS);
    }
    __syncthreads();

    // LN1 -> xsb (bf16, same rounding as the old ln1b round-trip)
    {
        const int row = t >> 6;
        const int c4  = (t & 63) * 4;
        float4 cv = *(const float4*)&Cp[0][row][c4];
        float4 g4 = *(const float4*)&gamma1[c4];
        const float m = mu[row], rd = rsd[row];
        bf16x4 o4;
        o4[0] = (short)f2b((cv.x - m) * rd * g4.x);
        o4[1] = (short)f2b((cv.y - m) * rd * g4.y);
        o4[2] = (short)f2b((cv.z - m) * rd * g4.z);
        o4[3] = (short)f2b((cv.w - m) * rd * g4.w);
        *(bf16x4*)&xsb[row][c4] = o4;
    }

    // ======== Phase 2: FFN GEMM1 -> hsb ========
    const int w = wave;
    f32x4 acc1[2];
    acc1[0] = zero; acc1[1] = zero;
    const unsigned short* b1frag = W1P + (size_t)(w * 2) * 4096 + (size_t)lane * 8;
    bf16x8 b10 = *(const bf16x8*)(b1frag);
    bf16x8 b11 = *(const bf16x8*)(b1frag + 4096);
    __syncthreads();   // xsb visible

#pragma unroll
    for (int ks = 0; ks < 8; ks++) {
        const int ksn = (ks + 1 < 8) ? ks + 1 : ks;
        bf16x8 n0 = *(const bf16x8*)(b1frag + ksn * 512);
        bf16x8 n1 = *(const bf16x8*)(b1frag + 4096 + ksn * 512);
        bf16x8 af = *(const bf16x8*)&xsb[c16][ks * 32 + quad * 8];
        acc1[0] = __builtin_amdgcn_mfma_f32_16x16x32_bf16(af, b10, acc1[0], 0, 0, 0);
        acc1[1] = __builtin_amdgcn_mfma_f32_16x16x32_bf16(af, b11, acc1[1], 0, 0, 0);
        b10 = n0; b11 = n1;
    }

#pragma unroll
    for (int nt = 0; nt < 2; nt++)
#pragma unroll
        for (int reg = 0; reg < 4; reg++)
            hsb[quad * 4 + reg][w * 32 + nt * 16 + c16] =
                f2b(fmaxf(acc1[nt][reg], 0.f));
    __syncthreads();

    // ======== Phase 3: FFN GEMM2 -> Cs ========
    f32x4 acc2 = zero;
    const unsigned short* b2frag = W2P + (size_t)w * 8192 + (size_t)lane * 8;
    bf16x8 b20 = *(const bf16x8*)(b2frag);
#pragma unroll
    for (int ks = 0; ks < 16; ks++) {
        const int ksn = (ks + 1 < 16) ? ks + 1 : ks;
        bf16x8 n0 = *(const bf16x8*)(b2frag + ksn * 512);
        bf16x8 af = *(const bf16x8*)&hsb[c16][ks * 32 + quad * 8];
        acc2 = __builtin_amdgcn_mfma_f32_16x16x32_bf16(af, b20, acc2, 0, 0, 0);
        b20 = n0;
    }
#pragma unroll
    for (int reg = 0; reg < 4; reg++)
        Cs[quad * 4 + reg][w * 16 + c16] = acc2[reg];
    __syncthreads();

    // ======== Phase 4: LN2 -> out ========
    if (t < 256) {
        const int row = t >> 4, seg = t & 15;
        float s = 0.f, s2 = 0.f;
#pragma unroll
        for (int j = 0; j < 16; j++) { float v = Cs[row][seg * 16 + j]; s += v; s2 += v * v; }
        ps1[row][seg] = s; ps2[row][seg] = s2;
    }
    __syncthreads();
    if (t < 16) {
        float s = 0.f, s2 = 0.f;
#pragma unroll
        for (int j = 0; j < 16; j++) { s += ps1[t][j]; s2 += ps2[t][j]; }
        float m = s * (1.0f / DIM);
        float var = s2 * (1.0f / DIM) - m * m;
        mu[t] = m;
        rsd[t] = rsqrtf(var + EPS);
    }
    __syncthreads();

    {
        const int row = t >> 6, c4 = (t & 63) * 4;
        float4 cv = *(const float4*)&Cs[row][c4];
        float4 g4 = *(const float4*)&gamma2[c4];
        const float m = mu[row], rd = rsd[row];
        float4 o;
        o.x = (cv.x - m) * rd * g4.x;
        o.y = (cv.y - m) * rd * g4.y;
        o.z = (cv.z - m) * rd * g4.z;
        o.w = (cv.w - m) * rd * g4.w;
        *(float4*)&out[(size_t)(r0 + row) * DIM + c4] = o;
    }
}

// ---------------------------------------------------------------------------
extern "C" void kernel_launch(void* const* d_in, const int* in_sizes, int n_in,
                              void* d_out, int out_size, void* d_ws, size_t ws_size,
                              hipStream_t stream) {
    const float* x      = (const float*)d_in[0];
    const float* Wq     = (const float*)d_in[1];
    const float* Wk     = (const float*)d_in[2];
    const float* Wv     = (const float*)d_in[3];
    const float* Wo     = (const float*)d_in[4];
    const float* Wf1    = (const float*)d_in[5];
    const float* Wf2    = (const float*)d_in[6];
    const float* gamma1 = (const float*)d_in[7];
    const float* gamma2 = (const float*)d_in[8];
    float* out = (float*)d_out;

    // workspace layout unchanged (ln1b slot now unused).
    char* base = (char*)d_ws;
    unsigned short* qb      = (unsigned short*)(base);              // 2 MB
    unsigned short* kb      = (unsigned short*)(base +  2097152);   // 2 MB
    unsigned short* VP      = (unsigned short*)(base +  4194304);   // 2 MB
    unsigned short* attoutb = (unsigned short*)(base +  6291456);   // 16 MB
    unsigned short* W1P     = (unsigned short*)(base + 41943040);   // 256 KB
    unsigned short* W2P     = (unsigned short*)(base + 42205184);   // 256 KB
    unsigned short* WoP     = (unsigned short*)(base + 44040192);   // 1 MB
    unsigned short* WqP     = (unsigned short*)(base + 45088768);   // 128 KB
    unsigned short* WkP     = (unsigned short*)(base + 45219840);   // 128 KB
    unsigned short* WvP     = (unsigned short*)(base + 45350912);   // 128 KB

    wprep<<<64, 256, 0, stream>>>(Wo, Wf1, Wf2, Wq, Wk, Wv,
                                  WoP, W1P, W2P, WqP, WkP, WvP);
    qkv_mfma<<<NROWS / 16, 1024, 0, stream>>>(x, WqP, WkP, WvP, qb, kb, VP);
    attn_mfma<<<(SEQ / 64) * HEADS * BATCH, 256, 0, stream>>>(qb, kb, VP, attoutb);
    wo_ffn_ln<<<NROWS / 16, 1024, 0, stream>>>(attoutb, WoP, x, gamma1,
                                               W1P, W2P, gamma2, out);
}